// Round 1
// baseline (1830.430 us; speedup 1.0000x reference)
//
#include <hip/hip_runtime.h>

// Problem constants (match reference)
#define D    128      // embedding dim
#define VSZ  200000   // vocab (emb has VSZ+1 rows, last row = 0)
#define NB   4096     // batch B
#define BSUP 1        // support batch
#define MM   50       // neighbors
#define DM   256      // 2*D
#define HSZ  512      // H
#define G4   2048     // 4*H
#define ROWS 16       // batch rows per GEMM block
#define VB   64       // emb rows per proj block

__device__ __forceinline__ float sigf(float x) { return 1.0f / (1.0f + __expf(-x)); }
__device__ __forceinline__ float tanhfast(float x) { return 1.0f - 2.0f / (__expf(2.0f * x) + 1.0f); }
__device__ __forceinline__ unsigned short f2bf(float x) {
    unsigned int u = __float_as_uint(x);
    u += 0x7FFFu + ((u >> 16) & 1u);   // round-to-nearest-even
    return (unsigned short)(u >> 16);
}
__device__ __forceinline__ float bf2f(unsigned short s) {
    return __uint_as_float(((unsigned int)s) << 16);
}

// ---------------------------------------------------------------------------
// Kernel 1: P1[v] = emb[v] @ W1.T + (gcn_lb+gcn_b),  P2[v] = emb[v] @ W2.T
// W1 = gcn_W[:, :128], W2 = gcn_W[:, 128:].  Output bf16.
// Lane = emb row (64 rows/block, 256 threads = 4 waves, each wave owns a
// 64-output chunk). W reads are wave-uniform -> scalar loads; e reads are
// per-lane LDS b32 at stride 129 (2-way bank alias = free).
// ---------------------------------------------------------------------------
__global__ __launch_bounds__(256) void k_proj_emb(
    const float* __restrict__ emb, const float* __restrict__ gcn_W,
    const float* __restrict__ gcn_lb, const float* __restrict__ gcn_b,
    unsigned short* __restrict__ P1, unsigned short* __restrict__ P2, int nrows)
{
    __shared__ float e[VB * 129];
    int t = threadIdx.x;
    int v0 = blockIdx.x * VB;
    // stage 64 emb rows (coalesced global float4, scalar LDS writes)
    for (int it = 0; it < 8; ++it) {
        int f = t + 256 * it;          // float4 index, 2048 total
        int r = f >> 5, c4 = f & 31;
        int v = v0 + r;
        float4 ev = make_float4(0.f, 0.f, 0.f, 0.f);
        if (v < nrows) ev = *(const float4*)(emb + (size_t)v * D + c4 * 4);
        float* dst = e + r * 129 + c4 * 4;
        dst[0] = ev.x; dst[1] = ev.y; dst[2] = ev.z; dst[3] = ev.w;
    }
    __syncthreads();

    int r = t & 63;
    int og = t >> 6;                   // wave-uniform
    int v = v0 + r;
    bool valid = (v < nrows);
    const float* erow = e + r * 129;

    for (int g = 0; g < 8; ++g) {
        int obase = og * 64 + g * 8;   // o = table*128 + d, 8 consecutive d
        int tbl = obase >> 7;
        int d0 = obase & 127;
        const float* wb = gcn_W + (size_t)d0 * DM + tbl * D;
        float acc[8];
        #pragma unroll
        for (int j = 0; j < 8; ++j) acc[j] = 0.f;
        #pragma unroll 4
        for (int c = 0; c < D; ++c) {
            float ec = erow[c];
            #pragma unroll
            for (int j = 0; j < 8; ++j)
                acc[j] += ec * wb[(size_t)j * DM + c];   // wave-uniform (s_load)
        }
        union { int4 v4; unsigned short us[8]; } pk;
        #pragma unroll
        for (int j = 0; j < 8; ++j) {
            float bsum = tbl ? 0.f : (gcn_lb[d0 + j] + gcn_b[d0 + j]);
            pk.us[j] = f2bf(acc[j] + bsum);
        }
        if (valid) {
            unsigned short* P = tbl ? P2 : P1;
            *(int4*)(P + (size_t)v * D + d0) = pk.v4;
        }
    }
}

// ---------------------------------------------------------------------------
// Kernel 2: neighbor aggregation. One block per (item, side); processes the
// two conn tables sequentially, averages, writes one 128-dim half of qv/sv.
// proj = gather(P1)+gather(P2) -> leakyrelu -> attn softmax over M -> agg
// -> gate -> gate*agg + (1-gate)*emb[self]
// ---------------------------------------------------------------------------
__global__ __launch_bounds__(256) void k_nbr(
    const int* __restrict__ query, const int* __restrict__ support,
    const int* __restrict__ q_l1, const int* __restrict__ q_l2,
    const int* __restrict__ q_r1, const int* __restrict__ q_r2,
    const int* __restrict__ s_l1, const int* __restrict__ s_l2,
    const int* __restrict__ s_r1, const int* __restrict__ s_r2,
    const unsigned short* __restrict__ P1, const unsigned short* __restrict__ P2,
    const float* __restrict__ emb,
    const float* __restrict__ attn_W, const float* __restrict__ attn_b,
    const float* __restrict__ gate_W, const float* __restrict__ gate_lb,
    const float* __restrict__ gate_b,
    float* __restrict__ qv, float* __restrict__ sv)
{
    __shared__ float proj[MM * (D + 1)];   // 50 x 129, pad kills bank conflicts
    __shared__ int rel[MM], ent[MM];
    __shared__ float sc[64];
    __shared__ float aw[D], gw[D];
    __shared__ float red[2];
    __shared__ float gateS;

    int bid = blockIdx.x;
    int item = bid >> 1;
    int side = bid & 1;
    int t = threadIdx.x;

    const int* cA; const int* cB; int selfid; float* outp;
    if (item < NB) {
        cA = (side ? q_r1 : q_l1) + (size_t)item * MM * 2;
        cB = (side ? q_r2 : q_l2) + (size_t)item * MM * 2;
        selfid = query[item * 2 + side];
        outp = qv + (size_t)item * DM + side * D;
    } else {
        int i2 = item - NB;
        cA = (side ? s_r1 : s_l1) + (size_t)i2 * MM * 2;
        cB = (side ? s_r2 : s_l2) + (size_t)i2 * MM * 2;
        selfid = support[i2 * 2 + side];
        outp = sv + (size_t)i2 * DM + side * D;
    }
    if (t < D) { aw[t] = attn_W[t]; gw[t] = gate_W[t]; }

    float acc_out = 0.f;
    for (int tab = 0; tab < 2; ++tab) {
        const int* conn = tab ? cB : cA;
        if (t < MM) { rel[t] = conn[t * 2]; ent[t] = conn[t * 2 + 1]; }
        __syncthreads();
        // phase A: gathered projection, leaky relu
        for (int e = t; e < MM * D; e += 256) {
            int m = e >> 7, d = e & 127;
            float p = bf2f(P1[(size_t)rel[m] * D + d]) + bf2f(P2[(size_t)ent[m] * D + d]);
            proj[m * (D + 1) + d] = (p >= 0.f) ? p : 0.01f * p;
        }
        __syncthreads();
        // phase B: attention scores
        if (t < MM) {
            float s = attn_b[0];
            const float* pr = proj + t * (D + 1);
            #pragma unroll 4
            for (int d = 0; d < D; ++d) s += pr[d] * aw[d];
            sc[t] = s;
        }
        __syncthreads();
        // softmax over M on wave 0
        if (t < 64) {
            float v = (t < MM) ? sc[t] : -1e30f;
            float mx = v;
            #pragma unroll
            for (int o = 32; o > 0; o >>= 1) mx = fmaxf(mx, __shfl_xor(mx, o, 64));
            float ev = (t < MM) ? __expf(v - mx) : 0.f;
            float sm = ev;
            #pragma unroll
            for (int o = 32; o > 0; o >>= 1) sm += __shfl_xor(sm, o, 64);
            if (t < MM) sc[t] = ev / sm;
        }
        __syncthreads();
        // phase C: weighted aggregation (thread = d)
        float agg = 0.f;
        if (t < D) {
            #pragma unroll 5
            for (int m = 0; m < MM; ++m) agg += sc[m] * proj[m * (D + 1) + t];
        }
        // phase D: gate scalar
        float gpart = (t < D) ? agg * gw[t] : 0.f;
        #pragma unroll
        for (int o = 32; o > 0; o >>= 1) gpart += __shfl_xor(gpart, o, 64);
        if (t == 0) red[0] = gpart;
        if (t == 64) red[1] = gpart;
        __syncthreads();
        if (t == 0) gateS = sigf(red[0] + red[1] + gate_lb[0] + gate_b[0]);
        __syncthreads();
        // phase E
        if (t < D) {
            float gval = gateS;
            acc_out += gval * agg + (1.f - gval) * emb[(size_t)selfid * D + t];
        }
        __syncthreads();
    }
    if (t < D) outp[t] = 0.5f * acc_out;
}

// ---------------------------------------------------------------------------
// Kernel 3: support vector -> sg (MLP residual + layernorm, ddof=1). 1 block.
// ---------------------------------------------------------------------------
__global__ __launch_bounds__(256) void k_sg(
    const float* __restrict__ sv,
    const float* __restrict__ p1_W, const float* __restrict__ p1_b,
    const float* __restrict__ p2_W, const float* __restrict__ p2_b,
    const float* __restrict__ ln_a, const float* __restrict__ ln_b,
    float* __restrict__ sg)
{
    __shared__ float s[DM];
    __shared__ float hid[2 * DM];
    __shared__ float h[DM];
    __shared__ float red[8];
    int t = threadIdx.x;
    s[t] = sv[t];
    __syncthreads();
    for (int j = t; j < 2 * DM; j += 256) {
        float a = p1_b[j];
        const float* w = p1_W + (size_t)j * DM;
        #pragma unroll 4
        for (int c = 0; c < DM; ++c) a += w[c] * s[c];
        hid[j] = fmaxf(a, 0.f);
    }
    __syncthreads();
    {
        float a = p2_b[t] + s[t];
        const float* w = p2_W + (size_t)t * 2 * DM;
        #pragma unroll 4
        for (int j = 0; j < 2 * DM; ++j) a += w[j] * hid[j];
        h[t] = a;
    }
    __syncthreads();
    float x = h[t];
    float sm = x;
    #pragma unroll
    for (int o = 32; o > 0; o >>= 1) sm += __shfl_xor(sm, o, 64);
    if ((t & 63) == 0) red[t >> 6] = sm;
    __syncthreads();
    float mu = (red[0] + red[1] + red[2] + red[3]) * (1.0f / 256.0f);
    float dv = x - mu;
    float sq = dv * dv;
    #pragma unroll
    for (int o = 32; o > 0; o >>= 1) sq += __shfl_xor(sq, o, 64);
    if ((t & 63) == 0) red[4 + (t >> 6)] = sq;
    __syncthreads();
    float var = (red[4] + red[5] + red[6] + red[7]) * (1.0f / 255.0f);  // ddof=1
    float sig = sqrtf(var);
    sg[t] = dv / (sig + 0.001f) * ln_a[t] + ln_b[t];
}

// ---------------------------------------------------------------------------
// Kernel 4: sgW[k] = sum_j sg[j] * Whh[k, 256+j]  (constant over batch)
// ---------------------------------------------------------------------------
__global__ __launch_bounds__(256) void k_sgwhh(
    const float* __restrict__ sg, const float* __restrict__ Whh,
    float* __restrict__ sgW)
{
    __shared__ float s[DM];
    int t = threadIdx.x;
    s[t] = sg[t];
    __syncthreads();
    int k = blockIdx.x * 256 + t;
    const float* w = Whh + (size_t)k * HSZ + DM;
    float a = 0.f;
    #pragma unroll 4
    for (int j = 0; j < DM; ++j) a += w[j] * s[j];
    sgW[k] = a;
}

// ---------------------------------------------------------------------------
// Kernel 5: g0[b][k] = qv[b] . Wih[k] + bih[k] + bhh[k]
// Register-tiled: thread owns 4 k-rows x 16 batch rows. qv via LDS b128
// broadcasts (wave-uniform address => no conflicts, low LDS issue rate).
// ---------------------------------------------------------------------------
__global__ __launch_bounds__(256) void k_g0(
    const float* __restrict__ qv, const float* __restrict__ Wih,
    const float* __restrict__ bih, const float* __restrict__ bhh,
    float* __restrict__ g0)
{
    __shared__ float q[ROWS * DM];
    int t = threadIdx.x;
    int b0 = blockIdx.x * ROWS;
    {
        const float4* src = (const float4*)(qv + (size_t)b0 * DM);
        float4* dst = (float4*)q;
        #pragma unroll
        for (int it = 0; it < 4; ++it) dst[t + 256 * it] = src[t + 256 * it];
    }
    __syncthreads();
    for (int u = 0; u < 2; ++u) {
        int k0 = u * 1024 + t * 4;
        float a0[ROWS], a1[ROWS], a2[ROWS], a3[ROWS];
        #pragma unroll
        for (int r = 0; r < ROWS; ++r) { a0[r] = 0.f; a1[r] = 0.f; a2[r] = 0.f; a3[r] = 0.f; }
        const float* wp = Wih + (size_t)k0 * DM;
        #pragma unroll 2
        for (int c = 0; c < DM; c += 4) {
            float4 w0 = *(const float4*)(wp + c);
            float4 w1 = *(const float4*)(wp + DM + c);
            float4 w2 = *(const float4*)(wp + 2 * DM + c);
            float4 w3 = *(const float4*)(wp + 3 * DM + c);
            #pragma unroll
            for (int r = 0; r < ROWS; ++r) {
                float4 qq = *(const float4*)&q[r * DM + c];
                a0[r] += w0.x * qq.x + w0.y * qq.y + w0.z * qq.z + w0.w * qq.w;
                a1[r] += w1.x * qq.x + w1.y * qq.y + w1.z * qq.z + w1.w * qq.w;
                a2[r] += w2.x * qq.x + w2.y * qq.y + w2.z * qq.z + w2.w * qq.w;
                a3[r] += w3.x * qq.x + w3.y * qq.y + w3.z * qq.z + w3.w * qq.w;
            }
        }
        float b0v = bih[k0 + 0] + bhh[k0 + 0];
        float b1v = bih[k0 + 1] + bhh[k0 + 1];
        float b2v = bih[k0 + 2] + bhh[k0 + 2];
        float b3v = bih[k0 + 3] + bhh[k0 + 3];
        #pragma unroll
        for (int r = 0; r < ROWS; ++r) {
            float4 o;
            o.x = a0[r] + b0v; o.y = a1[r] + b1v; o.z = a2[r] + b2v; o.w = a3[r] + b3v;
            *(float4*)(g0 + (size_t)(b0 + r) * G4 + k0) = o;
        }
    }
}

// ---------------------------------------------------------------------------
// Kernel 6: one LSTM step fused: gates(Gin, C) -> hq (LDS), then
// Gout[b][k] = g0[b][k] + sgW[k] + hq[b] . Whh[k, :256]
// Each block owns 16 batch rows; Gin==Gout in-place is safe (rows private).
// ---------------------------------------------------------------------------
__global__ __launch_bounds__(256) void k_step(
    const float* Gin, float* Gout,
    const float* __restrict__ g0, float* C,
    const float* __restrict__ qv, const float* __restrict__ sgW,
    const float* __restrict__ Whh, int first)
{
    __shared__ float hq[ROWS * DM];
    int t = threadIdx.x;
    int b0 = blockIdx.x * ROWS;
    // gating phase (covers all 512 k of all 16 rows)
    for (int idx = t; idx < ROWS * HSZ; idx += 256) {
        int r = idx >> 9, k = idx & (HSZ - 1);
        size_t gb = (size_t)(b0 + r) * G4;
        float gi = Gin[gb + k];
        float gf = Gin[gb + HSZ + k];
        float gg = Gin[gb + 2 * HSZ + k];
        float go = Gin[gb + 3 * HSZ + k];
        size_t cb = (size_t)(b0 + r) * HSZ + k;
        float cold = first ? 0.f : C[cb];
        float cn = sigf(gf) * cold + sigf(gi) * tanhfast(gg);
        C[cb] = cn;
        float hh = sigf(go) * tanhfast(cn);
        if (k < DM) hq[r * DM + k] = qv[(size_t)(b0 + r) * DM + k] + hh;
    }
    __syncthreads();
    // GEMM phase
    for (int u = 0; u < 2; ++u) {
        int k0 = u * 1024 + t * 4;
        float a0[ROWS], a1[ROWS], a2[ROWS], a3[ROWS];
        #pragma unroll
        for (int r = 0; r < ROWS; ++r) { a0[r] = 0.f; a1[r] = 0.f; a2[r] = 0.f; a3[r] = 0.f; }
        const float* wp = Whh + (size_t)k0 * HSZ;
        #pragma unroll 2
        for (int c = 0; c < DM; c += 4) {
            float4 w0 = *(const float4*)(wp + c);
            float4 w1 = *(const float4*)(wp + HSZ + c);
            float4 w2 = *(const float4*)(wp + 2 * HSZ + c);
            float4 w3 = *(const float4*)(wp + 3 * HSZ + c);
            #pragma unroll
            for (int r = 0; r < ROWS; ++r) {
                float4 qq = *(const float4*)&hq[r * DM + c];
                a0[r] += w0.x * qq.x + w0.y * qq.y + w0.z * qq.z + w0.w * qq.w;
                a1[r] += w1.x * qq.x + w1.y * qq.y + w1.z * qq.z + w1.w * qq.w;
                a2[r] += w2.x * qq.x + w2.y * qq.y + w2.z * qq.z + w2.w * qq.w;
                a3[r] += w3.x * qq.x + w3.y * qq.y + w3.z * qq.z + w3.w * qq.w;
            }
        }
        float s0 = sgW[k0 + 0], s1 = sgW[k0 + 1], s2 = sgW[k0 + 2], s3 = sgW[k0 + 3];
        #pragma unroll
        for (int r = 0; r < ROWS; ++r) {
            size_t gb = (size_t)(b0 + r) * G4 + k0;
            float4 gz = *(const float4*)(g0 + gb);
            float4 o;
            o.x = gz.x + s0 + a0[r];
            o.y = gz.y + s1 + a1[r];
            o.z = gz.z + s2 + a2[r];
            o.w = gz.w + s3 + a3[r];
            *(float4*)(Gout + gb) = o;
        }
    }
}

// ---------------------------------------------------------------------------
// Kernel 7: final gate (only k<256 matters) + out[b] = dot(qv+hh, sg)
// ---------------------------------------------------------------------------
__global__ __launch_bounds__(256) void k_final(
    const float* __restrict__ G, const float* __restrict__ C,
    const float* __restrict__ qv, const float* __restrict__ sg,
    float* __restrict__ out)
{
    __shared__ float red[4];
    int b = blockIdx.x, t = threadIdx.x;
    const float* g = G + (size_t)b * G4;
    float gi = g[t], gf = g[HSZ + t], gg = g[2 * HSZ + t], go = g[3 * HSZ + t];
    float cn = sigf(gf) * C[(size_t)b * HSZ + t] + sigf(gi) * tanhfast(gg);
    float hh = sigf(go) * tanhfast(cn);
    float h = qv[(size_t)b * DM + t] + hh;
    float p = h * sg[t];
    #pragma unroll
    for (int o = 32; o > 0; o >>= 1) p += __shfl_xor(p, o, 64);
    if ((t & 63) == 0) red[t >> 6] = p;
    __syncthreads();
    if (t == 0) out[b] = red[0] + red[1] + red[2] + red[3];
}

// ---------------------------------------------------------------------------
extern "C" void kernel_launch(void* const* d_in, const int* in_sizes, int n_in,
                              void* d_out, int out_size, void* d_ws, size_t ws_size,
                              hipStream_t stream) {
    const int* query   = (const int*)d_in[0];
    const int* support = (const int*)d_in[1];
    const int* q_l1 = (const int*)d_in[2];
    const int* q_l2 = (const int*)d_in[3];
    const int* q_r1 = (const int*)d_in[5];
    const int* q_r2 = (const int*)d_in[6];
    const int* s_l1 = (const int*)d_in[8];
    const int* s_l2 = (const int*)d_in[9];
    const int* s_r1 = (const int*)d_in[11];
    const int* s_r2 = (const int*)d_in[12];
    const float* emb    = (const float*)d_in[14];
    const float* gcn_W  = (const float*)d_in[15];
    const float* gcn_lb = (const float*)d_in[16];
    const float* gcn_b  = (const float*)d_in[17];
    const float* attn_W = (const float*)d_in[18];
    const float* attn_b = (const float*)d_in[19];
    const float* gate_W = (const float*)d_in[20];
    const float* gate_lb = (const float*)d_in[21];
    const float* gate_b  = (const float*)d_in[22];
    const float* p1_W = (const float*)d_in[23];
    const float* p1_b = (const float*)d_in[24];
    const float* p2_W = (const float*)d_in[25];
    const float* p2_b = (const float*)d_in[26];
    const float* ln_a = (const float*)d_in[27];
    const float* ln_b = (const float*)d_in[28];
    const float* Wih  = (const float*)d_in[29];
    const float* Whh  = (const float*)d_in[30];
    const float* bih  = (const float*)d_in[31];
    const float* bhh  = (const float*)d_in[32];

    // workspace layout (~182 MB total)
    unsigned short* P1 = (unsigned short*)d_ws;                 // (V+1)*128 bf16
    unsigned short* P2 = P1 + (size_t)(VSZ + 1) * D;            // (V+1)*128 bf16
    float* fws = (float*)(P2 + (size_t)(VSZ + 1) * D);          // 16B-aligned
    float* qvb = fws;  fws += (size_t)NB * DM;                  // 4 MB
    float* svb = fws;  fws += DM;
    float* sgb = fws;  fws += DM;
    float* sgW = fws;  fws += G4;
    float* g0b = fws;  fws += (size_t)NB * G4;                  // 32 MB
    float* Gb  = fws;  fws += (size_t)NB * G4;                  // 32 MB
    float* Cb  = fws;  fws += (size_t)NB * HSZ;                 // 8 MB
    (void)in_sizes; (void)n_in; (void)out_size; (void)ws_size;

    k_proj_emb<<<(VSZ + 1 + VB - 1) / VB, 256, 0, stream>>>(
        emb, gcn_W, gcn_lb, gcn_b, P1, P2, VSZ + 1);
    k_nbr<<<2 * (NB + BSUP), 256, 0, stream>>>(
        query, support, q_l1, q_l2, q_r1, q_r2, s_l1, s_l2, s_r1, s_r2,
        P1, P2, emb, attn_W, attn_b, gate_W, gate_lb, gate_b, qvb, svb);
    k_sg<<<1, 256, 0, stream>>>(svb, p1_W, p1_b, p2_W, p2_b, ln_a, ln_b, sgb);
    k_sgwhh<<<G4 / 256, 256, 0, stream>>>(sgb, Whh, sgW);
    k_g0<<<NB / ROWS, 256, 0, stream>>>(qvb, Wih, bih, bhh, g0b);
    k_step<<<NB / ROWS, 256, 0, stream>>>(g0b, Gb, g0b, Cb, qvb, sgW, Whh, 1);
    k_step<<<NB / ROWS, 256, 0, stream>>>(Gb,  Gb, g0b, Cb, qvb, sgW, Whh, 0);
    k_step<<<NB / ROWS, 256, 0, stream>>>(Gb,  Gb, g0b, Cb, qvb, sgW, Whh, 0);
    k_final<<<NB, 256, 0, stream>>>(Gb, Cb, qvb, sgb, (float*)d_out);
}

// Round 2
// 837.210 us; speedup vs baseline: 2.1863x; 2.1863x over previous
//
#include <hip/hip_runtime.h>

// Problem constants (match reference)
#define D    128      // embedding dim
#define VSZ  200000   // vocab (emb has VSZ+1 rows, last row = 0)
#define NB   4096     // batch B
#define MM   50       // neighbors
#define DM   256      // 2*D
#define HSZ  512      // H
#define G4   2048     // 4*H
#define ROWS 16       // batch rows per GEMM block

typedef __attribute__((ext_vector_type(8))) short short8;   // 8 bf16 = 4 VGPRs
typedef __attribute__((ext_vector_type(4))) float floatx4;  // MFMA acc

__device__ __forceinline__ float sigf(float x) { return 1.0f / (1.0f + __expf(-x)); }
__device__ __forceinline__ float tanhfast(float x) { return 1.0f - 2.0f / (__expf(2.0f * x) + 1.0f); }
__device__ __forceinline__ unsigned short f2bf(float x) {
    unsigned int u = __float_as_uint(x);
    u += 0x7FFFu + ((u >> 16) & 1u);   // round-to-nearest-even
    return (unsigned short)(u >> 16);
}
__device__ __forceinline__ float bf2f(unsigned short s) {
    return __uint_as_float(((unsigned int)s) << 16);
}

// ---------------------------------------------------------------------------
// Kernel 0: repack gcn_W (128x256 fp32, [d][c]) into bf16 Wb[n][k], n in
// [0,256), k in [0,128):  n<128 -> W[n][k] (P1 cols), n>=128 -> W[n-128][128+k]
// ---------------------------------------------------------------------------
__global__ __launch_bounds__(256) void k_wconv(
    const float* __restrict__ gcn_W, unsigned short* __restrict__ Wb)
{
    int i = blockIdx.x * 256 + threadIdx.x;     // 32768 total
    int n = i >> 7, k = i & 127;
    float v = (n < 128) ? gcn_W[n * 256 + k] : gcn_W[(n - 128) * 256 + 128 + k];
    Wb[i] = f2bf(v);
}

// ---------------------------------------------------------------------------
// Kernel 1: P = emb @ Wcat^T via bf16 MFMA.  Block: 64 emb rows x 256 cols,
// K=128.  4 waves; wave w owns 64 cols.  A staged fp32->bf16 in LDS
// (stride 136 shorts: 2-way bank alias only), B fragments register-resident.
// Epilogue adds (gcn_lb+gcn_b) to P1 cols, writes bf16.
// ---------------------------------------------------------------------------
__global__ __launch_bounds__(256) void k_proj_mfma(
    const float* __restrict__ emb, const unsigned short* __restrict__ Wb,
    const float* __restrict__ gcn_lb, const float* __restrict__ gcn_b,
    unsigned short* __restrict__ P1, unsigned short* __restrict__ P2, int nrows)
{
    __shared__ unsigned short A[64 * 136];
    int t = threadIdx.x;
    int v0 = blockIdx.x * 64;
    // stage A: 64 rows x 128 cols, fp32 -> bf16
    #pragma unroll
    for (int it = 0; it < 8; ++it) {
        int f = t + 256 * it;          // float4 index, 2048 total
        int r = f >> 5, c4 = f & 31;
        int v = v0 + r;
        float4 ev = make_float4(0.f, 0.f, 0.f, 0.f);
        if (v < nrows) ev = *(const float4*)(emb + (size_t)v * D + c4 * 4);
        ushort4 pk;
        pk.x = f2bf(ev.x); pk.y = f2bf(ev.y); pk.z = f2bf(ev.z); pk.w = f2bf(ev.w);
        *(ushort4*)(A + r * 136 + c4 * 4) = pk;
    }
    __syncthreads();

    int lane = t & 63;
    int w = t >> 6;
    int nl = lane & 15, quad = lane >> 4;
    int n0 = w * 64;

    // B fragments: 4 n-tiles x 4 k-steps, each lane 8 contiguous bf16 of row n
    short8 bf[4][4];
    #pragma unroll
    for (int nt = 0; nt < 4; ++nt)
        #pragma unroll
        for (int ks = 0; ks < 4; ++ks)
            bf[nt][ks] = *(const short8*)(Wb + (size_t)(n0 + nt * 16 + nl) * 128 + ks * 32 + quad * 8);

    floatx4 acc[4][4];
    #pragma unroll
    for (int mt = 0; mt < 4; ++mt)
        #pragma unroll
        for (int nt = 0; nt < 4; ++nt)
            acc[mt][nt] = (floatx4){0.f, 0.f, 0.f, 0.f};

    #pragma unroll
    for (int ks = 0; ks < 4; ++ks) {
        short8 af[4];
        #pragma unroll
        for (int mt = 0; mt < 4; ++mt)
            af[mt] = *(const short8*)(A + (mt * 16 + nl) * 136 + ks * 32 + quad * 8);
        #pragma unroll
        for (int mt = 0; mt < 4; ++mt)
            #pragma unroll
            for (int nt = 0; nt < 4; ++nt)
                acc[mt][nt] = __builtin_amdgcn_mfma_f32_16x16x32_bf16(
                    af[mt], bf[nt][ks], acc[mt][nt], 0, 0, 0);
    }

    // epilogue: C[row=v0+mt*16+quad*4+reg][col=n0+nt*16+nl]
    #pragma unroll
    for (int nt = 0; nt < 4; ++nt) {
        int col = n0 + nt * 16 + nl;
        float bias = 0.f;
        unsigned short* P;
        if (col < 128) { bias = gcn_lb[col] + gcn_b[col]; P = P1 + col; }
        else           { P = P2 + (col - 128); }
        #pragma unroll
        for (int mt = 0; mt < 4; ++mt)
            #pragma unroll
            for (int reg = 0; reg < 4; ++reg) {
                int v = v0 + mt * 16 + quad * 4 + reg;
                if (v < nrows) P[(size_t)v * D] = f2bf(acc[mt][nt][reg] + bias);
            }
    }
}

// ---------------------------------------------------------------------------
// Kernel 2: neighbor aggregation. One block per (item, side).
// ---------------------------------------------------------------------------
__global__ __launch_bounds__(256) void k_nbr(
    const int* __restrict__ query, const int* __restrict__ support,
    const int* __restrict__ q_l1, const int* __restrict__ q_l2,
    const int* __restrict__ q_r1, const int* __restrict__ q_r2,
    const int* __restrict__ s_l1, const int* __restrict__ s_l2,
    const int* __restrict__ s_r1, const int* __restrict__ s_r2,
    const unsigned short* __restrict__ P1, const unsigned short* __restrict__ P2,
    const float* __restrict__ emb,
    const float* __restrict__ attn_W, const float* __restrict__ attn_b,
    const float* __restrict__ gate_W, const float* __restrict__ gate_lb,
    const float* __restrict__ gate_b,
    float* __restrict__ qv, float* __restrict__ sv)
{
    __shared__ float proj[MM * 132];       // 50 x 132 (float4-aligned rows)
    __shared__ int rel[MM], ent[MM];
    __shared__ float sc[64];
    __shared__ float scp[4 * 64];
    __shared__ float aw[D], gw[D];
    __shared__ float red[2];
    __shared__ float gateS;

    int bid = blockIdx.x;
    int item = bid >> 1;
    int side = bid & 1;
    int t = threadIdx.x;

    const int* cA; const int* cB; int selfid; float* outp;
    if (item < NB) {
        cA = (side ? q_r1 : q_l1) + (size_t)item * MM * 2;
        cB = (side ? q_r2 : q_l2) + (size_t)item * MM * 2;
        selfid = query[item * 2 + side];
        outp = qv + (size_t)item * DM + side * D;
    } else {
        int i2 = item - NB;
        cA = (side ? s_r1 : s_l1) + (size_t)i2 * MM * 2;
        cB = (side ? s_r2 : s_l2) + (size_t)i2 * MM * 2;
        selfid = support[i2 * 2 + side];
        outp = sv + (size_t)i2 * DM + side * D;
    }
    if (t < D) { aw[t] = attn_W[t]; gw[t] = gate_W[t]; }

    float acc_out = 0.f;
    for (int tab = 0; tab < 2; ++tab) {
        const int* conn = tab ? cB : cA;
        if (t < MM) { rel[t] = conn[t * 2]; ent[t] = conn[t * 2 + 1]; }
        __syncthreads();
        // phase A: gathered projection (4 bf16 per load), leaky relu
        for (int e4 = t; e4 < MM * 32; e4 += 256) {
            int m = e4 >> 5, d4 = (e4 & 31) * 4;
            ushort4 a = *(const ushort4*)(P1 + (size_t)rel[m] * D + d4);
            ushort4 b = *(const ushort4*)(P2 + (size_t)ent[m] * D + d4);
            float4 p;
            p.x = bf2f(a.x) + bf2f(b.x);
            p.y = bf2f(a.y) + bf2f(b.y);
            p.z = bf2f(a.z) + bf2f(b.z);
            p.w = bf2f(a.w) + bf2f(b.w);
            p.x = (p.x >= 0.f) ? p.x : 0.01f * p.x;
            p.y = (p.y >= 0.f) ? p.y : 0.01f * p.y;
            p.z = (p.z >= 0.f) ? p.z : 0.01f * p.z;
            p.w = (p.w >= 0.f) ? p.w : 0.01f * p.w;
            *(float4*)(proj + m * 132 + d4) = p;
        }
        __syncthreads();
        // phase B: attention scores, 4 waves each do a 32-col slice
        {
            int m = t & 63, g = t >> 6;
            float s = 0.f;
            if (m < MM) {
                const float* pr = proj + m * 132 + g * 32;
                #pragma unroll 8
                for (int d = 0; d < 32; ++d) s += pr[d] * aw[g * 32 + d];
            }
            scp[g * 64 + m] = s;
        }
        __syncthreads();
        // softmax over M on wave 0
        if (t < 64) {
            float v = (t < MM) ? (scp[t] + scp[64 + t] + scp[128 + t] + scp[192 + t] + attn_b[0]) : -1e30f;
            float mx = v;
            #pragma unroll
            for (int o = 32; o > 0; o >>= 1) mx = fmaxf(mx, __shfl_xor(mx, o, 64));
            float ev = (t < MM) ? __expf(v - mx) : 0.f;
            float sm = ev;
            #pragma unroll
            for (int o = 32; o > 0; o >>= 1) sm += __shfl_xor(sm, o, 64);
            if (t < MM) sc[t] = ev / sm;
        }
        __syncthreads();
        // phase C: weighted aggregation (thread = d)
        float agg = 0.f;
        if (t < D) {
            #pragma unroll 5
            for (int m = 0; m < MM; ++m) agg += sc[m] * proj[m * 132 + t];
        }
        // phase D: gate scalar
        float gpart = (t < D) ? agg * gw[t] : 0.f;
        #pragma unroll
        for (int o = 32; o > 0; o >>= 1) gpart += __shfl_xor(gpart, o, 64);
        if (t == 0) red[0] = gpart;
        if (t == 64) red[1] = gpart;
        __syncthreads();
        if (t == 0) gateS = sigf(red[0] + red[1] + gate_lb[0] + gate_b[0]);
        __syncthreads();
        // phase E
        if (t < D) {
            float gval = gateS;
            acc_out += gval * agg + (1.f - gval) * emb[(size_t)selfid * D + t];
        }
        __syncthreads();
    }
    if (t < D) outp[t] = 0.5f * acc_out;
}

// ---------------------------------------------------------------------------
// Kernel 3: support vector -> sg (MLP residual + layernorm, ddof=1). 1 block.
// ---------------------------------------------------------------------------
__global__ __launch_bounds__(256) void k_sg(
    const float* __restrict__ sv,
    const float* __restrict__ p1_W, const float* __restrict__ p1_b,
    const float* __restrict__ p2_W, const float* __restrict__ p2_b,
    const float* __restrict__ ln_a, const float* __restrict__ ln_b,
    float* __restrict__ sg)
{
    __shared__ float s[DM];
    __shared__ float hid[2 * DM];
    __shared__ float h[DM];
    __shared__ float red[8];
    int t = threadIdx.x;
    s[t] = sv[t];
    __syncthreads();
    for (int j = t; j < 2 * DM; j += 256) {
        float a = p1_b[j];
        const float* w = p1_W + (size_t)j * DM;
        #pragma unroll 4
        for (int c = 0; c < DM; ++c) a += w[c] * s[c];
        hid[j] = fmaxf(a, 0.f);
    }
    __syncthreads();
    {
        float a = p2_b[t] + s[t];
        const float* w = p2_W + (size_t)t * 2 * DM;
        #pragma unroll 4
        for (int j = 0; j < 2 * DM; ++j) a += w[j] * hid[j];
        h[t] = a;
    }
    __syncthreads();
    float x = h[t];
    float sm = x;
    #pragma unroll
    for (int o = 32; o > 0; o >>= 1) sm += __shfl_xor(sm, o, 64);
    if ((t & 63) == 0) red[t >> 6] = sm;
    __syncthreads();
    float mu = (red[0] + red[1] + red[2] + red[3]) * (1.0f / 256.0f);
    float dv = x - mu;
    float sq = dv * dv;
    #pragma unroll
    for (int o = 32; o > 0; o >>= 1) sq += __shfl_xor(sq, o, 64);
    if ((t & 63) == 0) red[4 + (t >> 6)] = sq;
    __syncthreads();
    float var = (red[4] + red[5] + red[6] + red[7]) * (1.0f / 255.0f);  // ddof=1
    float sig = sqrtf(var);
    sg[t] = dv / (sig + 0.001f) * ln_a[t] + ln_b[t];
}

// ---------------------------------------------------------------------------
// Kernel 4: sgW[k] = sum_j sg[j] * Whh[k, 256+j]  (constant over batch)
// ---------------------------------------------------------------------------
__global__ __launch_bounds__(256) void k_sgwhh(
    const float* __restrict__ sg, const float* __restrict__ Whh,
    float* __restrict__ sgW)
{
    __shared__ float s[DM];
    int t = threadIdx.x;
    s[t] = sg[t];
    __syncthreads();
    int k = blockIdx.x * 256 + t;
    const float* w = Whh + (size_t)k * HSZ + DM;
    float a = 0.f;
    #pragma unroll 4
    for (int j = 0; j < DM; ++j) a += w[j] * s[j];
    sgW[k] = a;
}

// ---------------------------------------------------------------------------
// Kernel 5: g0[b][k] = qv[b] . Wih[k] + bih[k] + bhh[k]
// grid (NB/ROWS, 2); blockIdx.y picks the 1024-wide k-half.
// ---------------------------------------------------------------------------
__global__ __launch_bounds__(256) void k_g0(
    const float* __restrict__ qv, const float* __restrict__ Wih,
    const float* __restrict__ bih, const float* __restrict__ bhh,
    float* __restrict__ g0)
{
    __shared__ float q[ROWS * DM];
    int t = threadIdx.x;
    int b0 = blockIdx.x * ROWS;
    {
        const float4* src = (const float4*)(qv + (size_t)b0 * DM);
        float4* dst = (float4*)q;
        #pragma unroll
        for (int it = 0; it < 4; ++it) dst[t + 256 * it] = src[t + 256 * it];
    }
    __syncthreads();
    int k0 = blockIdx.y * 1024 + t * 4;
    float a0[ROWS], a1[ROWS], a2[ROWS], a3[ROWS];
    #pragma unroll
    for (int r = 0; r < ROWS; ++r) { a0[r] = 0.f; a1[r] = 0.f; a2[r] = 0.f; a3[r] = 0.f; }
    const float* wp = Wih + (size_t)k0 * DM;
    #pragma unroll 2
    for (int c = 0; c < DM; c += 4) {
        float4 w0 = *(const float4*)(wp + c);
        float4 w1 = *(const float4*)(wp + DM + c);
        float4 w2 = *(const float4*)(wp + 2 * DM + c);
        float4 w3 = *(const float4*)(wp + 3 * DM + c);
        #pragma unroll
        for (int r = 0; r < ROWS; ++r) {
            float4 qq = *(const float4*)&q[r * DM + c];
            a0[r] += w0.x * qq.x + w0.y * qq.y + w0.z * qq.z + w0.w * qq.w;
            a1[r] += w1.x * qq.x + w1.y * qq.y + w1.z * qq.z + w1.w * qq.w;
            a2[r] += w2.x * qq.x + w2.y * qq.y + w2.z * qq.z + w2.w * qq.w;
            a3[r] += w3.x * qq.x + w3.y * qq.y + w3.z * qq.z + w3.w * qq.w;
        }
    }
    float4 bi = *(const float4*)(bih + k0);
    float4 bh = *(const float4*)(bhh + k0);
    #pragma unroll
    for (int r = 0; r < ROWS; ++r) {
        float4 o;
        o.x = a0[r] + bi.x + bh.x; o.y = a1[r] + bi.y + bh.y;
        o.z = a2[r] + bi.z + bh.z; o.w = a3[r] + bi.w + bh.w;
        *(float4*)(g0 + (size_t)(b0 + r) * G4 + k0) = o;
    }
}

// ---------------------------------------------------------------------------
// Kernel 6a: gating (elementwise).  Reads Gin (pre-activations) + Cin,
// writes Cout and hq[b][k]=qv+hh for k<256.  Thread = 4 consecutive k.
// ---------------------------------------------------------------------------
__global__ __launch_bounds__(256) void k_gate(
    const float* __restrict__ Gin, const float* __restrict__ Cin,
    float* __restrict__ Cout, const float* __restrict__ qv,
    float* __restrict__ hqb, int first)
{
    int idx = blockIdx.x * 256 + threadIdx.x;   // over NB*512/4
    int b = idx >> 7, kq = (idx & 127) * 4;
    size_t gb = (size_t)b * G4;
    float4 gi = *(const float4*)(Gin + gb + kq);
    float4 gf = *(const float4*)(Gin + gb + HSZ + kq);
    float4 gg = *(const float4*)(Gin + gb + 2 * HSZ + kq);
    float4 go = *(const float4*)(Gin + gb + 3 * HSZ + kq);
    size_t cb = (size_t)b * HSZ + kq;
    float4 cold = first ? make_float4(0.f, 0.f, 0.f, 0.f) : *(const float4*)(Cin + cb);
    float4 cn, hh;
    cn.x = sigf(gf.x) * cold.x + sigf(gi.x) * tanhfast(gg.x);
    cn.y = sigf(gf.y) * cold.y + sigf(gi.y) * tanhfast(gg.y);
    cn.z = sigf(gf.z) * cold.z + sigf(gi.z) * tanhfast(gg.z);
    cn.w = sigf(gf.w) * cold.w + sigf(gi.w) * tanhfast(gg.w);
    *(float4*)(Cout + cb) = cn;
    if (kq < DM) {
        float4 q = *(const float4*)(qv + (size_t)b * DM + kq);
        hh.x = q.x + sigf(go.x) * tanhfast(cn.x);
        hh.y = q.y + sigf(go.y) * tanhfast(cn.y);
        hh.z = q.z + sigf(go.z) * tanhfast(cn.z);
        hh.w = q.w + sigf(go.w) * tanhfast(cn.w);
        *(float4*)(hqb + (size_t)b * DM + kq) = hh;
    }
}

// ---------------------------------------------------------------------------
// Kernel 6b: Gout[b][k] = g0[b][k] + sgW[k] + hq[b] . Whh[k, :256]
// grid (NB/ROWS, 2).
// ---------------------------------------------------------------------------
__global__ __launch_bounds__(256) void k_hhgemm(
    const float* __restrict__ hqb, const float* __restrict__ g0,
    const float* __restrict__ sgW, const float* __restrict__ Whh,
    float* __restrict__ Gout)
{
    __shared__ float hq[ROWS * DM];
    int t = threadIdx.x;
    int b0 = blockIdx.x * ROWS;
    {
        const float4* src = (const float4*)(hqb + (size_t)b0 * DM);
        float4* dst = (float4*)hq;
        #pragma unroll
        for (int it = 0; it < 4; ++it) dst[t + 256 * it] = src[t + 256 * it];
    }
    __syncthreads();
    int k0 = blockIdx.y * 1024 + t * 4;
    float a0[ROWS], a1[ROWS], a2[ROWS], a3[ROWS];
    #pragma unroll
    for (int r = 0; r < ROWS; ++r) { a0[r] = 0.f; a1[r] = 0.f; a2[r] = 0.f; a3[r] = 0.f; }
    const float* wp = Whh + (size_t)k0 * HSZ;
    #pragma unroll 2
    for (int c = 0; c < DM; c += 4) {
        float4 w0 = *(const float4*)(wp + c);
        float4 w1 = *(const float4*)(wp + HSZ + c);
        float4 w2 = *(const float4*)(wp + 2 * HSZ + c);
        float4 w3 = *(const float4*)(wp + 3 * HSZ + c);
        #pragma unroll
        for (int r = 0; r < ROWS; ++r) {
            float4 qq = *(const float4*)&hq[r * DM + c];
            a0[r] += w0.x * qq.x + w0.y * qq.y + w0.z * qq.z + w0.w * qq.w;
            a1[r] += w1.x * qq.x + w1.y * qq.y + w1.z * qq.z + w1.w * qq.w;
            a2[r] += w2.x * qq.x + w2.y * qq.y + w2.z * qq.z + w2.w * qq.w;
            a3[r] += w3.x * qq.x + w3.y * qq.y + w3.z * qq.z + w3.w * qq.w;
        }
    }
    float4 s4 = *(const float4*)(sgW + k0);
    #pragma unroll
    for (int r = 0; r < ROWS; ++r) {
        size_t gb = (size_t)(b0 + r) * G4 + k0;
        float4 gz = *(const float4*)(g0 + gb);
        float4 o;
        o.x = gz.x + s4.x + a0[r];
        o.y = gz.y + s4.y + a1[r];
        o.z = gz.z + s4.z + a2[r];
        o.w = gz.w + s4.w + a3[r];
        *(float4*)(Gout + gb) = o;
    }
}

// ---------------------------------------------------------------------------
// Kernel 7: final gate (only k<256 matters) + out[b] = dot(qv+hh, sg)
// ---------------------------------------------------------------------------
__global__ __launch_bounds__(256) void k_final(
    const float* __restrict__ G, const float* __restrict__ C,
    const float* __restrict__ qv, const float* __restrict__ sg,
    float* __restrict__ out)
{
    __shared__ float red[4];
    int b = blockIdx.x, t = threadIdx.x;
    const float* g = G + (size_t)b * G4;
    float gi = g[t], gf = g[HSZ + t], gg = g[2 * HSZ + t], go = g[3 * HSZ + t];
    float cn = sigf(gf) * C[(size_t)b * HSZ + t] + sigf(gi) * tanhfast(gg);
    float hh = sigf(go) * tanhfast(cn);
    float h = qv[(size_t)b * DM + t] + hh;
    float p = h * sg[t];
    #pragma unroll
    for (int o = 32; o > 0; o >>= 1) p += __shfl_xor(p, o, 64);
    if ((t & 63) == 0) red[t >> 6] = p;
    __syncthreads();
    if (t == 0) out[b] = red[0] + red[1] + red[2] + red[3];
}

// ---------------------------------------------------------------------------
extern "C" void kernel_launch(void* const* d_in, const int* in_sizes, int n_in,
                              void* d_out, int out_size, void* d_ws, size_t ws_size,
                              hipStream_t stream) {
    const int* query   = (const int*)d_in[0];
    const int* support = (const int*)d_in[1];
    const int* q_l1 = (const int*)d_in[2];
    const int* q_l2 = (const int*)d_in[3];
    const int* q_r1 = (const int*)d_in[5];
    const int* q_r2 = (const int*)d_in[6];
    const int* s_l1 = (const int*)d_in[8];
    const int* s_l2 = (const int*)d_in[9];
    const int* s_r1 = (const int*)d_in[11];
    const int* s_r2 = (const int*)d_in[12];
    const float* emb    = (const float*)d_in[14];
    const float* gcn_W  = (const float*)d_in[15];
    const float* gcn_lb = (const float*)d_in[16];
    const float* gcn_b  = (const float*)d_in[17];
    const float* attn_W = (const float*)d_in[18];
    const float* attn_b = (const float*)d_in[19];
    const float* gate_W = (const float*)d_in[20];
    const float* gate_lb = (const float*)d_in[21];
    const float* gate_b  = (const float*)d_in[22];
    const float* p1_W = (const float*)d_in[23];
    const float* p1_b = (const float*)d_in[24];
    const float* p2_W = (const float*)d_in[25];
    const float* p2_b = (const float*)d_in[26];
    const float* ln_a = (const float*)d_in[27];
    const float* ln_b = (const float*)d_in[28];
    const float* Wih  = (const float*)d_in[29];
    const float* Whh  = (const float*)d_in[30];
    const float* bih  = (const float*)d_in[31];
    const float* bhh  = (const float*)d_in[32];

    // workspace layout (~191 MB)
    unsigned short* P1 = (unsigned short*)d_ws;                 // (V+1)*128 bf16
    unsigned short* P2 = P1 + (size_t)(VSZ + 1) * D;            // (V+1)*128 bf16
    unsigned short* Wb = P2 + (size_t)(VSZ + 1) * D;            // 256*128 bf16
    float* fws = (float*)(Wb + 256 * 128);
    float* qvb = fws;  fws += (size_t)NB * DM;                  // 4 MB
    float* svb = fws;  fws += DM;
    float* sgb = fws;  fws += DM;
    float* sgW = fws;  fws += G4;
    float* g0b = fws;  fws += (size_t)NB * G4;                  // 32 MB
    float* Gb  = fws;  fws += (size_t)NB * G4;                  // 32 MB
    float* Ca  = fws;  fws += (size_t)NB * HSZ;                 // 8 MB
    float* Cb  = fws;  fws += (size_t)NB * HSZ;                 // 8 MB
    float* hqb = fws;  fws += (size_t)NB * DM;                  // 4 MB
    (void)in_sizes; (void)n_in; (void)out_size; (void)ws_size;

    k_wconv<<<128, 256, 0, stream>>>(gcn_W, Wb);
    k_proj_mfma<<<(VSZ + 1 + 63) / 64, 256, 0, stream>>>(
        emb, Wb, gcn_lb, gcn_b, P1, P2, VSZ + 1);
    k_nbr<<<2 * (NB + 1), 256, 0, stream>>>(
        query, support, q_l1, q_l2, q_r1, q_r2, s_l1, s_l2, s_r1, s_r2,
        P1, P2, emb, attn_W, attn_b, gate_W, gate_lb, gate_b, qvb, svb);
    k_sg<<<1, 256, 0, stream>>>(svb, p1_W, p1_b, p2_W, p2_b, ln_a, ln_b, sgb);
    k_sgwhh<<<G4 / 256, 256, 0, stream>>>(sgb, Whh, sgW);
    k_g0<<<dim3(NB / ROWS, 2), 256, 0, stream>>>(qvb, Wih, bih, bhh, g0b);
    // step 1 gates come from g0 (h_r = 0), C from 0
    k_gate<<<NB * HSZ / 1024, 256, 0, stream>>>(g0b, Ca, Ca, qvb, hqb, 1);
    k_hhgemm<<<dim3(NB / ROWS, 2), 256, 0, stream>>>(hqb, g0b, sgW, Whh, Gb);
    k_gate<<<NB * HSZ / 1024, 256, 0, stream>>>(Gb, Ca, Cb, qvb, hqb, 0);
    k_hhgemm<<<dim3(NB / ROWS, 2), 256, 0, stream>>>(hqb, g0b, sgW, Whh, Gb);
    k_gate<<<NB * HSZ / 1024, 256, 0, stream>>>(Gb, Cb, Ca, qvb, hqb, 0);
    k_hhgemm<<<dim3(NB / ROWS, 2), 256, 0, stream>>>(hqb, g0b, sgW, Whh, Gb);
    k_final<<<NB, 256, 0, stream>>>(Gb, Ca, qvb, sgb, (float*)d_out);
}

// Round 3
// 777.980 us; speedup vs baseline: 2.3528x; 1.0761x over previous
//
#include <hip/hip_runtime.h>

// Problem constants (match reference)
#define D    128      // embedding dim
#define VSZ  200000   // vocab (emb has VSZ+1 rows, last row = 0)
#define NB   4096     // batch B
#define MM   50       // neighbors
#define DM   256      // 2*D
#define HSZ  512      // H
#define G4   2048     // 4*H

typedef __attribute__((ext_vector_type(8))) short short8;   // 8 bf16 = 4 VGPRs
typedef __attribute__((ext_vector_type(4))) float floatx4;  // MFMA acc

__device__ __forceinline__ float sigf(float x) { return 1.0f / (1.0f + __expf(-x)); }
__device__ __forceinline__ float tanhfast(float x) { return 1.0f - 2.0f / (__expf(2.0f * x) + 1.0f); }
__device__ __forceinline__ unsigned short f2bf(float x) {
    unsigned int u = __float_as_uint(x);
    u += 0x7FFFu + ((u >> 16) & 1u);   // round-to-nearest-even
    return (unsigned short)(u >> 16);
}
__device__ __forceinline__ float bf2f(unsigned short s) {
    return __uint_as_float(((unsigned int)s) << 16);
}

// ---------------------------------------------------------------------------
// Kernel 0: repack gcn_W (128x256 fp32, [d][c]) into bf16 Wb[n][k] for proj.
// ---------------------------------------------------------------------------
__global__ __launch_bounds__(256) void k_wconv(
    const float* __restrict__ gcn_W, unsigned short* __restrict__ Wb)
{
    int i = blockIdx.x * 256 + threadIdx.x;     // 32768 total
    int n = i >> 7, k = i & 127;
    float v = (n < 128) ? gcn_W[n * 256 + k] : gcn_W[(n - 128) * 256 + 128 + k];
    Wb[i] = f2bf(v);
}

// ---------------------------------------------------------------------------
// Kernel 0b: pack Wih (2048x256) and Whh[:, :256] (2048 rows, stride 512)
// into fragment-linear bf16 for mfma_f32_16x16x32_bf16 B-operand:
//   chunk idx = (tile*8 + ks)*64 + lane, 8 bf16 per chunk
//   n = tile*16 + (lane&15), k = ks*32 + (lane>>4)*8
// Also gb[n] = bih[n] + bhh[n].
// ---------------------------------------------------------------------------
__global__ __launch_bounds__(256) void k_pack(
    const float* __restrict__ Wih, const float* __restrict__ Whh,
    const float* __restrict__ bih, const float* __restrict__ bhh,
    unsigned short* __restrict__ Wihp, unsigned short* __restrict__ Whhp,
    float* __restrict__ gb)
{
    int idx = blockIdx.x * 256 + threadIdx.x;
    if (idx < 131072) {
        int ci = idx & 65535;
        int lane = ci & 63, rest = ci >> 6;
        int ks = rest & 7, tile = rest >> 3;
        int n = tile * 16 + (lane & 15), k = ks * 32 + (lane >> 4) * 8;
        const float* src = (idx < 65536) ? (Wih + (size_t)n * 256 + k)
                                         : (Whh + (size_t)n * 512 + k);
        unsigned short* dst = (idx < 65536) ? Wihp : Whhp;
        short8 o;
        #pragma unroll
        for (int j = 0; j < 8; ++j) o[j] = (short)f2bf(src[j]);
        *(short8*)(dst + (size_t)ci * 8) = o;
    } else if (idx < 131072 + 2048) {
        int i = idx - 131072;
        gb[i] = bih[i] + bhh[i];
    }
}

// ---------------------------------------------------------------------------
// Kernel 1: P = emb @ Wcat^T via bf16 MFMA.  Block: 64 emb rows x 256 cols.
// ---------------------------------------------------------------------------
__global__ __launch_bounds__(256) void k_proj_mfma(
    const float* __restrict__ emb, const unsigned short* __restrict__ Wb,
    const float* __restrict__ gcn_lb, const float* __restrict__ gcn_b,
    unsigned short* __restrict__ P1, unsigned short* __restrict__ P2, int nrows)
{
    __shared__ unsigned short A[64 * 136];
    int t = threadIdx.x;
    int v0 = blockIdx.x * 64;
    #pragma unroll
    for (int it = 0; it < 8; ++it) {
        int f = t + 256 * it;          // float4 index, 2048 total
        int r = f >> 5, c4 = f & 31;
        int v = v0 + r;
        float4 ev = make_float4(0.f, 0.f, 0.f, 0.f);
        if (v < nrows) ev = *(const float4*)(emb + (size_t)v * D + c4 * 4);
        ushort4 pk;
        pk.x = f2bf(ev.x); pk.y = f2bf(ev.y); pk.z = f2bf(ev.z); pk.w = f2bf(ev.w);
        *(ushort4*)(A + r * 136 + c4 * 4) = pk;
    }
    __syncthreads();

    int lane = t & 63;
    int w = t >> 6;
    int nl = lane & 15, quad = lane >> 4;
    int n0 = w * 64;

    short8 bf[4][4];
    #pragma unroll
    for (int nt = 0; nt < 4; ++nt)
        #pragma unroll
        for (int ks = 0; ks < 4; ++ks)
            bf[nt][ks] = *(const short8*)(Wb + (size_t)(n0 + nt * 16 + nl) * 128 + ks * 32 + quad * 8);

    floatx4 acc[4][4];
    #pragma unroll
    for (int mt = 0; mt < 4; ++mt)
        #pragma unroll
        for (int nt = 0; nt < 4; ++nt)
            acc[mt][nt] = (floatx4){0.f, 0.f, 0.f, 0.f};

    #pragma unroll
    for (int ks = 0; ks < 4; ++ks) {
        short8 af[4];
        #pragma unroll
        for (int mt = 0; mt < 4; ++mt)
            af[mt] = *(const short8*)(A + (mt * 16 + nl) * 136 + ks * 32 + quad * 8);
        #pragma unroll
        for (int mt = 0; mt < 4; ++mt)
            #pragma unroll
            for (int nt = 0; nt < 4; ++nt)
                acc[mt][nt] = __builtin_amdgcn_mfma_f32_16x16x32_bf16(
                    af[mt], bf[nt][ks], acc[mt][nt], 0, 0, 0);
    }

    #pragma unroll
    for (int nt = 0; nt < 4; ++nt) {
        int col = n0 + nt * 16 + nl;
        float bias = 0.f;
        unsigned short* P;
        if (col < 128) { bias = gcn_lb[col] + gcn_b[col]; P = P1 + col; }
        else           { P = P2 + (col - 128); }
        #pragma unroll
        for (int mt = 0; mt < 4; ++mt)
            #pragma unroll
            for (int reg = 0; reg < 4; ++reg) {
                int v = v0 + mt * 16 + quad * 4 + reg;
                if (v < nrows) P[(size_t)v * D] = f2bf(acc[mt][nt][reg] + bias);
            }
    }
}

// ---------------------------------------------------------------------------
// Kernel 2: neighbor aggregation. One block per (item, side).
// ---------------------------------------------------------------------------
__global__ __launch_bounds__(256) void k_nbr(
    const int* __restrict__ query, const int* __restrict__ support,
    const int* __restrict__ q_l1, const int* __restrict__ q_l2,
    const int* __restrict__ q_r1, const int* __restrict__ q_r2,
    const int* __restrict__ s_l1, const int* __restrict__ s_l2,
    const int* __restrict__ s_r1, const int* __restrict__ s_r2,
    const unsigned short* __restrict__ P1, const unsigned short* __restrict__ P2,
    const float* __restrict__ emb,
    const float* __restrict__ attn_W, const float* __restrict__ attn_b,
    const float* __restrict__ gate_W, const float* __restrict__ gate_lb,
    const float* __restrict__ gate_b,
    float* __restrict__ qv, float* __restrict__ sv)
{
    __shared__ float proj[MM * 132];
    __shared__ int rel[MM], ent[MM];
    __shared__ float sc[64];
    __shared__ float scp[4 * 64];
    __shared__ float aw[D], gw[D];
    __shared__ float red[2];
    __shared__ float gateS;

    int bid = blockIdx.x;
    int item = bid >> 1;
    int side = bid & 1;
    int t = threadIdx.x;

    const int* cA; const int* cB; int selfid; float* outp;
    if (item < NB) {
        cA = (side ? q_r1 : q_l1) + (size_t)item * MM * 2;
        cB = (side ? q_r2 : q_l2) + (size_t)item * MM * 2;
        selfid = query[item * 2 + side];
        outp = qv + (size_t)item * DM + side * D;
    } else {
        int i2 = item - NB;
        cA = (side ? s_r1 : s_l1) + (size_t)i2 * MM * 2;
        cB = (side ? s_r2 : s_l2) + (size_t)i2 * MM * 2;
        selfid = support[i2 * 2 + side];
        outp = sv + (size_t)i2 * DM + side * D;
    }
    if (t < D) { aw[t] = attn_W[t]; gw[t] = gate_W[t]; }

    float acc_out = 0.f;
    for (int tab = 0; tab < 2; ++tab) {
        const int* conn = tab ? cB : cA;
        if (t < MM) { rel[t] = conn[t * 2]; ent[t] = conn[t * 2 + 1]; }
        __syncthreads();
        for (int e4 = t; e4 < MM * 32; e4 += 256) {
            int m = e4 >> 5, d4 = (e4 & 31) * 4;
            ushort4 a = *(const ushort4*)(P1 + (size_t)rel[m] * D + d4);
            ushort4 b = *(const ushort4*)(P2 + (size_t)ent[m] * D + d4);
            float4 p;
            p.x = bf2f(a.x) + bf2f(b.x);
            p.y = bf2f(a.y) + bf2f(b.y);
            p.z = bf2f(a.z) + bf2f(b.z);
            p.w = bf2f(a.w) + bf2f(b.w);
            p.x = (p.x >= 0.f) ? p.x : 0.01f * p.x;
            p.y = (p.y >= 0.f) ? p.y : 0.01f * p.y;
            p.z = (p.z >= 0.f) ? p.z : 0.01f * p.z;
            p.w = (p.w >= 0.f) ? p.w : 0.01f * p.w;
            *(float4*)(proj + m * 132 + d4) = p;
        }
        __syncthreads();
        {
            int m = t & 63, g = t >> 6;
            float s = 0.f;
            if (m < MM) {
                const float* pr = proj + m * 132 + g * 32;
                #pragma unroll 8
                for (int d = 0; d < 32; ++d) s += pr[d] * aw[g * 32 + d];
            }
            scp[g * 64 + m] = s;
        }
        __syncthreads();
        if (t < 64) {
            float v = (t < MM) ? (scp[t] + scp[64 + t] + scp[128 + t] + scp[192 + t] + attn_b[0]) : -1e30f;
            float mx = v;
            #pragma unroll
            for (int o = 32; o > 0; o >>= 1) mx = fmaxf(mx, __shfl_xor(mx, o, 64));
            float ev = (t < MM) ? __expf(v - mx) : 0.f;
            float sm = ev;
            #pragma unroll
            for (int o = 32; o > 0; o >>= 1) sm += __shfl_xor(sm, o, 64);
            if (t < MM) sc[t] = ev / sm;
        }
        __syncthreads();
        float agg = 0.f;
        if (t < D) {
            #pragma unroll 5
            for (int m = 0; m < MM; ++m) agg += sc[m] * proj[m * 132 + t];
        }
        float gpart = (t < D) ? agg * gw[t] : 0.f;
        #pragma unroll
        for (int o = 32; o > 0; o >>= 1) gpart += __shfl_xor(gpart, o, 64);
        if (t == 0) red[0] = gpart;
        if (t == 64) red[1] = gpart;
        __syncthreads();
        if (t == 0) gateS = sigf(red[0] + red[1] + gate_lb[0] + gate_b[0]);
        __syncthreads();
        if (t < D) {
            float gval = gateS;
            acc_out += gval * agg + (1.f - gval) * emb[(size_t)selfid * D + t];
        }
        __syncthreads();
    }
    if (t < D) outp[t] = 0.5f * acc_out;
}

// ---------------------------------------------------------------------------
// Kernel 3: support vector -> sg (MLP residual + layernorm, ddof=1). 1 block.
// ---------------------------------------------------------------------------
__global__ __launch_bounds__(256) void k_sg(
    const float* __restrict__ sv,
    const float* __restrict__ p1_W, const float* __restrict__ p1_b,
    const float* __restrict__ p2_W, const float* __restrict__ p2_b,
    const float* __restrict__ ln_a, const float* __restrict__ ln_b,
    float* __restrict__ sg)
{
    __shared__ float s[DM];
    __shared__ float hid[2 * DM];
    __shared__ float h[DM];
    __shared__ float red[8];
    int t = threadIdx.x;
    s[t] = sv[t];
    __syncthreads();
    for (int j = t; j < 2 * DM; j += 256) {
        float a = p1_b[j];
        const float* w = p1_W + (size_t)j * DM;
        #pragma unroll 4
        for (int c = 0; c < DM; ++c) a += w[c] * s[c];
        hid[j] = fmaxf(a, 0.f);
    }
    __syncthreads();
    {
        float a = p2_b[t] + s[t];
        const float* w = p2_W + (size_t)t * 2 * DM;
        #pragma unroll 4
        for (int j = 0; j < 2 * DM; ++j) a += w[j] * hid[j];
        h[t] = a;
    }
    __syncthreads();
    float x = h[t];
    float sm = x;
    #pragma unroll
    for (int o = 32; o > 0; o >>= 1) sm += __shfl_xor(sm, o, 64);
    if ((t & 63) == 0) red[t >> 6] = sm;
    __syncthreads();
    float mu = (red[0] + red[1] + red[2] + red[3]) * (1.0f / 256.0f);
    float dv = x - mu;
    float sq = dv * dv;
    #pragma unroll
    for (int o = 32; o > 0; o >>= 1) sq += __shfl_xor(sq, o, 64);
    if ((t & 63) == 0) red[4 + (t >> 6)] = sq;
    __syncthreads();
    float var = (red[4] + red[5] + red[6] + red[7]) * (1.0f / 255.0f);  // ddof=1
    float sig = sqrtf(var);
    sg[t] = dv / (sig + 0.001f) * ln_a[t] + ln_b[t];
}

// ---------------------------------------------------------------------------
// Kernel 4: sgW[k] = sum_j sg[j] * Whh[k, 256+j]  (constant over batch)
// ---------------------------------------------------------------------------
__global__ __launch_bounds__(256) void k_sgwhh(
    const float* __restrict__ sg, const float* __restrict__ Whh,
    float* __restrict__ sgW)
{
    __shared__ float s[DM];
    int t = threadIdx.x;
    s[t] = sg[t];
    __syncthreads();
    int k = blockIdx.x * 256 + t;
    const float* w = Whh + (size_t)k * HSZ + DM;
    float a = 0.f;
    #pragma unroll 4
    for (int j = 0; j < DM; ++j) a += w[j] * s[j];
    sgW[k] = a;
}

// ---------------------------------------------------------------------------
// Kernel 5: fused LSTM step via MFMA. One block = 16 batch rows x 2048 cols,
// K=256.  Wave w owns n-tiles {w, w+4, ..., w+124}; since 512/16 = 32 = 0
// (mod 4), all four gates (k, k+512, k+1024, k+1536) of any k live in the
// SAME wave's accumulators -> gate nonlinearity fused in-register.
//   mode 0: A = bf16(qv), B = Wihp.  g = A@B + gb; store g0=bf16(g);
//           c = sig(i)*tanh(g); C=c; hq = qv + sig(o)*tanh(c)  (k<256)
//   mode 1: A = hq(bf16), B = Whhp. g = A@B + g0 + sgW; c update; hq out.
//   mode 2: like 1, but no C/hq store; out[b] = dot(qv+hh, sg).
// B is packed fragment-linear: each wave load = 1 coalesced dwordx4 (1 KB).
// ---------------------------------------------------------------------------
__global__ __launch_bounds__(256, 1) void k_lstm(
    const float* __restrict__ qv, const unsigned short* __restrict__ hqin,
    const unsigned short* __restrict__ Bp,
    const float* __restrict__ gb, const float* __restrict__ sgW,
    const unsigned short* __restrict__ g0i, unsigned short* __restrict__ g0o,
    float* __restrict__ C, unsigned short* __restrict__ hqo,
    const float* __restrict__ sg, float* __restrict__ out, int mode)
{
    __shared__ float red[4][16];
    int t = threadIdx.x;
    int lane = t & 63, w = t >> 6;
    int nl = lane & 15, quad = lane >> 4;
    int b0 = blockIdx.x * 16;

    floatx4 acc[32];
    #pragma unroll
    for (int j = 0; j < 32; ++j) acc[j] = (floatx4){0.f, 0.f, 0.f, 0.f};

    for (int ks = 0; ks < 8; ++ks) {
        short8 af;
        if (mode == 0) {
            const float* qp = qv + (size_t)(b0 + nl) * DM + ks * 32 + quad * 8;
            #pragma unroll
            for (int j = 0; j < 8; ++j) af[j] = (short)f2bf(qp[j]);
        } else {
            af = *(const short8*)(hqin + (size_t)(b0 + nl) * DM + ks * 32 + quad * 8);
        }
        #pragma unroll
        for (int j = 0; j < 32; ++j) {
            int tile = w + 4 * j;
            short8 bfr = *(const short8*)(Bp + ((size_t)(tile * 8 + ks) * 64 + lane) * 8);
            acc[j] = __builtin_amdgcn_mfma_f32_16x16x32_bf16(af, bfr, acc[j], 0, 0, 0);
        }
    }

    float preg[4] = {0.f, 0.f, 0.f, 0.f};
    #pragma unroll
    for (int j = 0; j < 8; ++j) {
        int coli = (w + 4 * j) * 16 + nl;          // i-gate col == C index k
        floatx4 iv = acc[j], fv = acc[j + 8], gv = acc[j + 16], ov = acc[j + 24];
        if (mode == 0) {
            float bi = gb[coli], bff = gb[coli + 512];
            float bg = gb[coli + 1024], bo = gb[coli + 1536];
            #pragma unroll
            for (int r = 0; r < 4; ++r) {
                int b = b0 + quad * 4 + r;
                float gi_ = iv[r] + bi, gf_ = fv[r] + bff;
                float gg_ = gv[r] + bg, go_ = ov[r] + bo;
                size_t gbase = (size_t)b * G4;
                g0o[gbase + coli]        = f2bf(gi_);
                g0o[gbase + coli + 512]  = f2bf(gf_);
                g0o[gbase + coli + 1024] = f2bf(gg_);
                g0o[gbase + coli + 1536] = f2bf(go_);
                float cn = sigf(gi_) * tanhfast(gg_);
                C[(size_t)b * HSZ + coli] = cn;
                if (j < 4) {
                    float h = qv[(size_t)b * DM + coli] + sigf(go_) * tanhfast(cn);
                    hqo[(size_t)b * DM + coli] = f2bf(h);
                }
            }
        } else {
            float si = sgW[coli], sf = sgW[coli + 512];
            float sgg = sgW[coli + 1024], so = sgW[coli + 1536];
            #pragma unroll
            for (int r = 0; r < 4; ++r) {
                int b = b0 + quad * 4 + r;
                size_t gbase = (size_t)b * G4;
                float gi_ = iv[r] + si  + bf2f(g0i[gbase + coli]);
                float gf_ = fv[r] + sf  + bf2f(g0i[gbase + coli + 512]);
                float gg_ = gv[r] + sgg + bf2f(g0i[gbase + coli + 1024]);
                float go_ = ov[r] + so  + bf2f(g0i[gbase + coli + 1536]);
                float cold = C[(size_t)b * HSZ + coli];
                float cn = sigf(gf_) * cold + sigf(gi_) * tanhfast(gg_);
                if (mode == 1) C[(size_t)b * HSZ + coli] = cn;
                if (j < 4) {
                    float h = qv[(size_t)b * DM + coli] + sigf(go_) * tanhfast(cn);
                    if (mode == 1) hqo[(size_t)b * DM + coli] = f2bf(h);
                    else           preg[r] += h * sg[coli];
                }
            }
        }
    }

    if (mode == 2) {
        #pragma unroll
        for (int r = 0; r < 4; ++r) {
            float p = preg[r];
            p += __shfl_xor(p, 1, 64);
            p += __shfl_xor(p, 2, 64);
            p += __shfl_xor(p, 4, 64);
            p += __shfl_xor(p, 8, 64);
            if (nl == 0) red[w][quad * 4 + r] = p;
        }
        __syncthreads();
        if (t < 16) out[b0 + t] = red[0][t] + red[1][t] + red[2][t] + red[3][t];
    }
}

// ---------------------------------------------------------------------------
extern "C" void kernel_launch(void* const* d_in, const int* in_sizes, int n_in,
                              void* d_out, int out_size, void* d_ws, size_t ws_size,
                              hipStream_t stream) {
    const int* query   = (const int*)d_in[0];
    const int* support = (const int*)d_in[1];
    const int* q_l1 = (const int*)d_in[2];
    const int* q_l2 = (const int*)d_in[3];
    const int* q_r1 = (const int*)d_in[5];
    const int* q_r2 = (const int*)d_in[6];
    const int* s_l1 = (const int*)d_in[8];
    const int* s_l2 = (const int*)d_in[9];
    const int* s_r1 = (const int*)d_in[11];
    const int* s_r2 = (const int*)d_in[12];
    const float* emb    = (const float*)d_in[14];
    const float* gcn_W  = (const float*)d_in[15];
    const float* gcn_lb = (const float*)d_in[16];
    const float* gcn_b  = (const float*)d_in[17];
    const float* attn_W = (const float*)d_in[18];
    const float* attn_b = (const float*)d_in[19];
    const float* gate_W = (const float*)d_in[20];
    const float* gate_lb = (const float*)d_in[21];
    const float* gate_b  = (const float*)d_in[22];
    const float* p1_W = (const float*)d_in[23];
    const float* p1_b = (const float*)d_in[24];
    const float* p2_W = (const float*)d_in[25];
    const float* p2_b = (const float*)d_in[26];
    const float* ln_a = (const float*)d_in[27];
    const float* ln_b = (const float*)d_in[28];
    const float* Wih  = (const float*)d_in[29];
    const float* Whh  = (const float*)d_in[30];
    const float* bih  = (const float*)d_in[31];
    const float* bhh  = (const float*)d_in[32];

    // workspace layout (~135 MB): bf16 buffers first, then fp32
    unsigned short* P1   = (unsigned short*)d_ws;               // (V+1)*128
    unsigned short* P2   = P1 + (size_t)(VSZ + 1) * D;
    unsigned short* Wb   = P2 + (size_t)(VSZ + 1) * D;          // 256*128
    unsigned short* Wihp = Wb + 256 * 128;                      // 65536*8
    unsigned short* Whhp = Wihp + (size_t)65536 * 8;            // 65536*8
    unsigned short* g0b  = Whhp + (size_t)65536 * 8;            // NB*2048
    unsigned short* hqb  = g0b + (size_t)NB * G4;               // NB*256
    float* fws = (float*)(hqb + (size_t)NB * DM);
    float* gbv = fws;  fws += G4;
    float* qvb = fws;  fws += (size_t)NB * DM;                  // 4 MB
    float* svb = fws;  fws += DM;
    float* sgb = fws;  fws += DM;
    float* sgW = fws;  fws += G4;
    float* Cb  = fws;  fws += (size_t)NB * HSZ;                 // 8 MB
    (void)in_sizes; (void)n_in; (void)out_size; (void)ws_size;

    k_wconv<<<128, 256, 0, stream>>>(gcn_W, Wb);
    k_pack<<<(131072 + 2048) / 256, 256, 0, stream>>>(
        Wih, Whh, bih, bhh, Wihp, Whhp, gbv);
    k_proj_mfma<<<(VSZ + 1 + 63) / 64, 256, 0, stream>>>(
        emb, Wb, gcn_lb, gcn_b, P1, P2, VSZ + 1);
    k_nbr<<<2 * (NB + 1), 256, 0, stream>>>(
        query, support, q_l1, q_l2, q_r1, q_r2, s_l1, s_l2, s_r1, s_r2,
        P1, P2, emb, attn_W, attn_b, gate_W, gate_lb, gate_b, qvb, svb);
    k_sg<<<1, 256, 0, stream>>>(svb, p1_W, p1_b, p2_W, p2_b, ln_a, ln_b, sgb);
    k_sgwhh<<<G4 / 256, 256, 0, stream>>>(sgb, Whh, sgW);
    // step 1 (h_r = 0): GEMM vs Wih, store g0 (bf16, biases folded), gate
    k_lstm<<<NB / 16, 256, 0, stream>>>(
        qvb, hqb, Wihp, gbv, sgW, g0b, g0b, Cb, hqb, sgb, (float*)d_out, 0);
    // steps 2,3: GEMM vs Whh[:, :256], g = g0 + sgW + hq@Whh.T, gate
    k_lstm<<<NB / 16, 256, 0, stream>>>(
        qvb, hqb, Whhp, gbv, sgW, g0b, g0b, Cb, hqb, sgb, (float*)d_out, 1);
    k_lstm<<<NB / 16, 256, 0, stream>>>(
        qvb, hqb, Whhp, gbv, sgW, g0b, g0b, Cb, hqb, sgb, (float*)d_out, 1);
    // step 4: gate + fused dot(h, sg) -> out
    k_lstm<<<NB / 16, 256, 0, stream>>>(
        qvb, hqb, Whhp, gbv, sgW, g0b, g0b, Cb, hqb, sgb, (float*)d_out, 2);
}

// Round 4
// 503.781 us; speedup vs baseline: 3.6334x; 1.5443x over previous
//
#include <hip/hip_runtime.h>

// Problem constants (match reference)
#define D    128      // embedding dim
#define VSZ  200000   // vocab (emb has VSZ+1 rows, last row = 0)
#define NB   4096     // batch B
#define MM   50       // neighbors
#define DM   256      // 2*D
#define HSZ  512      // H
#define G4   2048     // 4*H

typedef __attribute__((ext_vector_type(8))) short short8;   // 8 bf16 = 4 VGPRs
typedef __attribute__((ext_vector_type(4))) float floatx4;  // MFMA acc

__device__ __forceinline__ float sigf(float x) { return 1.0f / (1.0f + __expf(-x)); }
__device__ __forceinline__ float tanhfast(float x) { return 1.0f - 2.0f / (__expf(2.0f * x) + 1.0f); }
__device__ __forceinline__ unsigned short f2bf(float x) {
    unsigned int u = __float_as_uint(x);
    u += 0x7FFFu + ((u >> 16) & 1u);   // round-to-nearest-even
    return (unsigned short)(u >> 16);
}
__device__ __forceinline__ float bf2f(unsigned short s) {
    return __uint_as_float(((unsigned int)s) << 16);
}

// ---------------------------------------------------------------------------
// Kernel 0: repack gcn_W (128x256 fp32, [d][c]) into bf16 Wb[n][k] for proj.
// ---------------------------------------------------------------------------
__global__ __launch_bounds__(256) void k_wconv(
    const float* __restrict__ gcn_W, unsigned short* __restrict__ Wb)
{
    int i = blockIdx.x * 256 + threadIdx.x;     // 32768 total
    int n = i >> 7, k = i & 127;
    float v = (n < 128) ? gcn_W[n * 256 + k] : gcn_W[(n - 128) * 256 + 128 + k];
    Wb[i] = f2bf(v);
}

// ---------------------------------------------------------------------------
// Kernel 0b: pack Wih (2048x256) and Whh[:, :256] into fragment-linear bf16:
//   chunk idx = (tile*8 + ks)*64 + lane, 8 bf16 per chunk
//   n = tile*16 + (lane&15), k = ks*32 + (lane>>4)*8.  Also gb = bih + bhh.
// ---------------------------------------------------------------------------
__global__ __launch_bounds__(256) void k_pack(
    const float* __restrict__ Wih, const float* __restrict__ Whh,
    const float* __restrict__ bih, const float* __restrict__ bhh,
    unsigned short* __restrict__ Wihp, unsigned short* __restrict__ Whhp,
    float* __restrict__ gb)
{
    int idx = blockIdx.x * 256 + threadIdx.x;
    if (idx < 131072) {
        int ci = idx & 65535;
        int lane = ci & 63, rest = ci >> 6;
        int ks = rest & 7, tile = rest >> 3;
        int n = tile * 16 + (lane & 15), k = ks * 32 + (lane >> 4) * 8;
        const float* src = (idx < 65536) ? (Wih + (size_t)n * 256 + k)
                                         : (Whh + (size_t)n * 512 + k);
        unsigned short* dst = (idx < 65536) ? Wihp : Whhp;
        short8 o;
        #pragma unroll
        for (int j = 0; j < 8; ++j) o[j] = (short)f2bf(src[j]);
        *(short8*)(dst + (size_t)ci * 8) = o;
    } else if (idx < 131072 + 2048) {
        int i = idx - 131072;
        gb[i] = bih[i] + bhh[i];
    }
}

// ---------------------------------------------------------------------------
// Kernel 1: P = emb @ Wcat^T via bf16 MFMA.  Block: 64 emb rows x 256 cols.
// Epilogue: transpose acc through LDS -> fully coalesced dwordx4 stores
// (round-3 counters showed 2B column-strided stores caused +50% write
// amplification and 51 MB of RMW fetch).
// ---------------------------------------------------------------------------
__global__ __launch_bounds__(256) void k_proj_mfma(
    const float* __restrict__ emb, const unsigned short* __restrict__ Wb,
    const float* __restrict__ gcn_lb, const float* __restrict__ gcn_b,
    unsigned short* __restrict__ P1, unsigned short* __restrict__ P2, int nrows)
{
    __shared__ unsigned short S[64 * 264];   // A stage (stride 136) / C stage (stride 264)
    int t = threadIdx.x;
    int v0 = blockIdx.x * 64;
    // stage A: 64 rows x 128 cols, fp32 -> bf16, stride 136 shorts
    #pragma unroll
    for (int it = 0; it < 8; ++it) {
        int f = t + 256 * it;          // float4 index, 2048 total
        int r = f >> 5, c4 = f & 31;
        int v = v0 + r;
        float4 ev = make_float4(0.f, 0.f, 0.f, 0.f);
        if (v < nrows) ev = *(const float4*)(emb + (size_t)v * D + c4 * 4);
        ushort4 pk;
        pk.x = f2bf(ev.x); pk.y = f2bf(ev.y); pk.z = f2bf(ev.z); pk.w = f2bf(ev.w);
        *(ushort4*)(S + r * 136 + c4 * 4) = pk;
    }
    __syncthreads();

    int lane = t & 63;
    int w = t >> 6;
    int nl = lane & 15, quad = lane >> 4;
    int n0 = w * 64;

    short8 bf[4][4];
    #pragma unroll
    for (int nt = 0; nt < 4; ++nt)
        #pragma unroll
        for (int ks = 0; ks < 4; ++ks)
            bf[nt][ks] = *(const short8*)(Wb + (size_t)(n0 + nt * 16 + nl) * 128 + ks * 32 + quad * 8);

    floatx4 acc[4][4];
    #pragma unroll
    for (int mt = 0; mt < 4; ++mt)
        #pragma unroll
        for (int nt = 0; nt < 4; ++nt)
            acc[mt][nt] = (floatx4){0.f, 0.f, 0.f, 0.f};

    #pragma unroll
    for (int ks = 0; ks < 4; ++ks) {
        short8 af[4];
        #pragma unroll
        for (int mt = 0; mt < 4; ++mt)
            af[mt] = *(const short8*)(S + (mt * 16 + nl) * 136 + ks * 32 + quad * 8);
        #pragma unroll
        for (int mt = 0; mt < 4; ++mt)
            #pragma unroll
            for (int nt = 0; nt < 4; ++nt)
                acc[mt][nt] = __builtin_amdgcn_mfma_f32_16x16x32_bf16(
                    af[mt], bf[nt][ks], acc[mt][nt], 0, 0, 0);
    }

    __syncthreads();   // done reading A region; reuse S as C stage
    // write C tile to LDS: row = local emb row, col = output feature (bf16)
    #pragma unroll
    for (int nt = 0; nt < 4; ++nt) {
        int col = n0 + nt * 16 + nl;
        float bias = (col < 128) ? (gcn_lb[col] + gcn_b[col]) : 0.f;
        #pragma unroll
        for (int mt = 0; mt < 4; ++mt)
            #pragma unroll
            for (int reg = 0; reg < 4; ++reg)
                S[(mt * 16 + quad * 4 + reg) * 264 + col] = f2bf(acc[mt][nt][reg] + bias);
    }
    __syncthreads();
    // coalesced store: 2048 16B chunks; chunk c -> row c>>5, 8-short chunk c&31
    #pragma unroll
    for (int it = 0; it < 8; ++it) {
        int c = t + 256 * it;
        int row = c >> 5, c8 = c & 31;
        int v = v0 + row;
        if (v < nrows) {
            int4 val = *(const int4*)(S + row * 264 + c8 * 8);
            unsigned short* dst = (c8 < 16) ? (P1 + (size_t)v * D + c8 * 8)
                                            : (P2 + (size_t)v * D + (c8 - 16) * 8);
            *(int4*)dst = val;
        }
    }
}

// ---------------------------------------------------------------------------
// Kernel 2: neighbor aggregation, both conn tables concurrently.
// One block per (item, side).  proj staged bf16 in LDS (100 x 136 shorts).
// ---------------------------------------------------------------------------
__global__ __launch_bounds__(256) void k_nbr(
    const int* __restrict__ query, const int* __restrict__ support,
    const int* __restrict__ q_l1, const int* __restrict__ q_l2,
    const int* __restrict__ q_r1, const int* __restrict__ q_r2,
    const int* __restrict__ s_l1, const int* __restrict__ s_l2,
    const int* __restrict__ s_r1, const int* __restrict__ s_r2,
    const unsigned short* __restrict__ P1, const unsigned short* __restrict__ P2,
    const float* __restrict__ emb,
    const float* __restrict__ attn_W, const float* __restrict__ attn_b,
    const float* __restrict__ gate_W, const float* __restrict__ gate_lb,
    const float* __restrict__ gate_b,
    float* __restrict__ qv, unsigned short* __restrict__ qvbf,
    float* __restrict__ sv)
{
    __shared__ unsigned short proj[2 * MM * 136];   // bf16, 27.2 KB
    __shared__ int rel[2 * MM], ent[2 * MM];
    __shared__ float scw[2 * 64];
    __shared__ float scp[2][2][64];
    __shared__ float aw[D], gw[D];
    __shared__ float redg[4];
    __shared__ float gateS[2];
    __shared__ float oth[D];

    int bid = blockIdx.x;
    int item = bid >> 1;
    int side = bid & 1;
    int t = threadIdx.x;

    const int* cA; const int* cB; int selfid; float* outp; bool isq;
    if (item < NB) {
        isq = true;
        cA = (side ? q_r1 : q_l1) + (size_t)item * MM * 2;
        cB = (side ? q_r2 : q_l2) + (size_t)item * MM * 2;
        selfid = query[item * 2 + side];
        outp = qv + (size_t)item * DM + side * D;
    } else {
        isq = false;
        int i2 = item - NB;
        cA = (side ? s_r1 : s_l1) + (size_t)i2 * MM * 2;
        cB = (side ? s_r2 : s_l2) + (size_t)i2 * MM * 2;
        selfid = support[i2 * 2 + side];
        outp = sv + (size_t)i2 * DM + side * D;
    }
    if (t < D) { aw[t] = attn_W[t]; gw[t] = gate_W[t]; }
    if (t < 2 * MM) {
        const int* c = (t < MM) ? cA : cB;
        int m = (t < MM) ? t : t - MM;
        rel[t] = c[m * 2]; ent[t] = c[m * 2 + 1];
    }
    __syncthreads();
    // gather + leakyrelu -> bf16 LDS
    for (int e4 = t; e4 < 2 * MM * 32; e4 += 256) {
        int m = e4 >> 5, d4 = (e4 & 31) * 4;
        ushort4 a = *(const ushort4*)(P1 + (size_t)rel[m] * D + d4);
        ushort4 b = *(const ushort4*)(P2 + (size_t)ent[m] * D + d4);
        float p0 = bf2f(a.x) + bf2f(b.x);
        float p1 = bf2f(a.y) + bf2f(b.y);
        float p2 = bf2f(a.z) + bf2f(b.z);
        float p3 = bf2f(a.w) + bf2f(b.w);
        p0 = (p0 >= 0.f) ? p0 : 0.01f * p0;
        p1 = (p1 >= 0.f) ? p1 : 0.01f * p1;
        p2 = (p2 >= 0.f) ? p2 : 0.01f * p2;
        p3 = (p3 >= 0.f) ? p3 : 0.01f * p3;
        ushort4 o;
        o.x = f2bf(p0); o.y = f2bf(p1); o.z = f2bf(p2); o.w = f2bf(p3);
        *(ushort4*)(proj + m * 136 + d4) = o;
    }
    __syncthreads();
    // scores: tab = t>>7, half g = (t>>6)&1, m = t&63 (m<50 valid)
    {
        int tab = t >> 7, g = (t >> 6) & 1, m = t & 63;
        float s = 0.f;
        if (m < MM) {
            const unsigned short* pr = proj + (tab * MM + m) * 136 + g * 64;
            #pragma unroll
            for (int i = 0; i < 8; ++i) {
                short8 v8 = *(const short8*)(pr + i * 8);
                #pragma unroll
                for (int j = 0; j < 8; ++j)
                    s += bf2f((unsigned short)v8[j]) * aw[g * 64 + i * 8 + j];
            }
        }
        scp[tab][g][m] = s;
    }
    __syncthreads();
    // softmax per table: wave 0 -> tabA, wave 1 -> tabB
    if (t < 128) {
        int tab = t >> 6, m = t & 63;
        float v = (m < MM) ? (scp[tab][0][m] + scp[tab][1][m] + attn_b[0]) : -1e30f;
        float mx = v;
        #pragma unroll
        for (int o = 32; o > 0; o >>= 1) mx = fmaxf(mx, __shfl_xor(mx, o, 64));
        float ev = (m < MM) ? __expf(v - mx) : 0.f;
        float sm = ev;
        #pragma unroll
        for (int o = 32; o > 0; o >>= 1) sm += __shfl_xor(sm, o, 64);
        if (m < MM) scw[tab * 64 + m] = ev / sm;
    }
    __syncthreads();
    // agg: tab = t>>7, d = t&127
    int tab = t >> 7, d = t & 127;
    float agg = 0.f;
    #pragma unroll 5
    for (int m = 0; m < MM; ++m)
        agg += scw[tab * 64 + m] * bf2f(proj[(tab * MM + m) * 136 + d]);
    // gate scalar per table (2 waves each)
    float gpart = agg * gw[d];
    #pragma unroll
    for (int o = 32; o > 0; o >>= 1) gpart += __shfl_xor(gpart, o, 64);
    if ((t & 63) == 0) redg[t >> 6] = gpart;
    __syncthreads();
    if (t == 0)  gateS[0] = sigf(redg[0] + redg[1] + gate_lb[0] + gate_b[0]);
    if (t == 64) gateS[1] = sigf(redg[2] + redg[3] + gate_lb[0] + gate_b[0]);
    __syncthreads();
    float embd = emb[(size_t)selfid * D + d];
    float val = gateS[tab] * agg + (1.f - gateS[tab]) * embd;
    if (tab == 1) oth[d] = val;
    __syncthreads();
    if (tab == 0) {
        float r = 0.5f * (val + oth[d]);
        outp[d] = r;
        if (isq) qvbf[(size_t)item * DM + side * D + d] = f2bf(r);
    }
}

// ---------------------------------------------------------------------------
// Kernel 3: support vector -> sg (MLP residual + layernorm, ddof=1). 1 block.
// ---------------------------------------------------------------------------
__global__ __launch_bounds__(256) void k_sg(
    const float* __restrict__ sv,
    const float* __restrict__ p1_W, const float* __restrict__ p1_b,
    const float* __restrict__ p2_W, const float* __restrict__ p2_b,
    const float* __restrict__ ln_a, const float* __restrict__ ln_b,
    float* __restrict__ sg)
{
    __shared__ float s[DM];
    __shared__ float hid[2 * DM];
    __shared__ float h[DM];
    __shared__ float red[8];
    int t = threadIdx.x;
    s[t] = sv[t];
    __syncthreads();
    for (int j = t; j < 2 * DM; j += 256) {
        float a = p1_b[j];
        const float* w = p1_W + (size_t)j * DM;
        #pragma unroll 4
        for (int c = 0; c < DM; ++c) a += w[c] * s[c];
        hid[j] = fmaxf(a, 0.f);
    }
    __syncthreads();
    {
        float a = p2_b[t] + s[t];
        const float* w = p2_W + (size_t)t * 2 * DM;
        #pragma unroll 4
        for (int j = 0; j < 2 * DM; ++j) a += w[j] * hid[j];
        h[t] = a;
    }
    __syncthreads();
    float x = h[t];
    float sm = x;
    #pragma unroll
    for (int o = 32; o > 0; o >>= 1) sm += __shfl_xor(sm, o, 64);
    if ((t & 63) == 0) red[t >> 6] = sm;
    __syncthreads();
    float mu = (red[0] + red[1] + red[2] + red[3]) * (1.0f / 256.0f);
    float dv = x - mu;
    float sq = dv * dv;
    #pragma unroll
    for (int o = 32; o > 0; o >>= 1) sq += __shfl_xor(sq, o, 64);
    if ((t & 63) == 0) red[4 + (t >> 6)] = sq;
    __syncthreads();
    float var = (red[4] + red[5] + red[6] + red[7]) * (1.0f / 255.0f);  // ddof=1
    float sig = sqrtf(var);
    sg[t] = dv / (sig + 0.001f) * ln_a[t] + ln_b[t];
}

// ---------------------------------------------------------------------------
// Kernel 4: sgW[k] = sum_j sg[j] * Whh[k, 256+j]  (constant over batch)
// ---------------------------------------------------------------------------
__global__ __launch_bounds__(256) void k_sgwhh(
    const float* __restrict__ sg, const float* __restrict__ Whh,
    float* __restrict__ sgW)
{
    __shared__ float s[DM];
    int t = threadIdx.x;
    s[t] = sg[t];
    __syncthreads();
    int k = blockIdx.x * 256 + t;
    const float* w = Whh + (size_t)k * HSZ + DM;
    float a = 0.f;
    #pragma unroll 4
    for (int j = 0; j < DM; ++j) a += w[j] * s[j];
    sgW[k] = a;
}

// ---------------------------------------------------------------------------
// Kernel 5: zero d_out (it is poisoned before every timed launch; the final
// LSTM step accumulates into it with atomics).
// ---------------------------------------------------------------------------
__global__ __launch_bounds__(256) void k_zero(float* __restrict__ p)
{
    p[blockIdx.x * 256 + threadIdx.x] = 0.f;
}

// ---------------------------------------------------------------------------
// Kernel 6: fused LSTM step via MFMA, n-split 4 ways for occupancy.
// grid (NB/16, 4); block = 16 batch rows x 512 cols.  Wave w owns n-tiles
// T ∈ {T0, T0+1}, T0 = blockIdx.y*8 + w*2, plus their gate tiles T+32g.
// All four gates of col k=T*16+nl live in the same wave -> fused epilogue.
//   mode 0: A = qv(bf16), B = Wihp. g = A@B + gb; store g0 bf16; C; hq.
//   mode 1: A = hq,       B = Whhp. g = A@B + g0 + sgW; C; hq.
//   mode 2: (launch y<2 only) like 1 but no stores; atomicAdd dot(h,sg).
// ---------------------------------------------------------------------------
__global__ __launch_bounds__(256, 4) void k_lstm(
    const float* __restrict__ qv, const unsigned short* __restrict__ Ain,
    const unsigned short* __restrict__ Bp,
    const float* __restrict__ gb, const float* __restrict__ sgW,
    const unsigned short* __restrict__ g0i, unsigned short* __restrict__ g0o,
    float* __restrict__ C, unsigned short* __restrict__ hqo,
    const float* __restrict__ sg, float* __restrict__ out, int mode)
{
    __shared__ float red[4][16];
    int t = threadIdx.x;
    int lane = t & 63, w = t >> 6;
    int nl = lane & 15, quad = lane >> 4;
    int b0 = blockIdx.x * 16;
    int T0 = blockIdx.y * 8 + w * 2;

    floatx4 acc[2][4];
    #pragma unroll
    for (int tt = 0; tt < 2; ++tt)
        #pragma unroll
        for (int g = 0; g < 4; ++g) acc[tt][g] = (floatx4){0.f, 0.f, 0.f, 0.f};

    for (int ks = 0; ks < 8; ++ks) {
        short8 af = *(const short8*)(Ain + (size_t)(b0 + nl) * DM + ks * 32 + quad * 8);
        #pragma unroll
        for (int tt = 0; tt < 2; ++tt)
            #pragma unroll
            for (int g = 0; g < 4; ++g) {
                int tile = T0 + tt + 32 * g;
                short8 bfr = *(const short8*)(Bp + ((size_t)(tile * 8 + ks) * 64 + lane) * 8);
                acc[tt][g] = __builtin_amdgcn_mfma_f32_16x16x32_bf16(af, bfr, acc[tt][g], 0, 0, 0);
            }
    }

    float preg[4] = {0.f, 0.f, 0.f, 0.f};
    #pragma unroll
    for (int tt = 0; tt < 2; ++tt) {
        int T = T0 + tt;
        int coli = T * 16 + nl;
        floatx4 iv = acc[tt][0], fv = acc[tt][1], gv = acc[tt][2], ov = acc[tt][3];
        if (mode == 0) {
            float bi = gb[coli], bff = gb[coli + 512];
            float bg = gb[coli + 1024], bo = gb[coli + 1536];
            #pragma unroll
            for (int r = 0; r < 4; ++r) {
                int b = b0 + quad * 4 + r;
                float gi_ = iv[r] + bi, gf_ = fv[r] + bff;
                float gg_ = gv[r] + bg, go_ = ov[r] + bo;
                size_t gbase = (size_t)b * G4;
                g0o[gbase + coli]        = f2bf(gi_);
                g0o[gbase + coli + 512]  = f2bf(gf_);
                g0o[gbase + coli + 1024] = f2bf(gg_);
                g0o[gbase + coli + 1536] = f2bf(go_);
                float cn = sigf(gi_) * tanhfast(gg_);
                C[(size_t)b * HSZ + coli] = cn;
                if (T < 16) {
                    float h = qv[(size_t)b * DM + coli] + sigf(go_) * tanhfast(cn);
                    hqo[(size_t)b * DM + coli] = f2bf(h);
                }
                (void)gf_;
            }
        } else {
            float si = sgW[coli], sf = sgW[coli + 512];
            float sgg = sgW[coli + 1024], so = sgW[coli + 1536];
            #pragma unroll
            for (int r = 0; r < 4; ++r) {
                int b = b0 + quad * 4 + r;
                size_t gbase = (size_t)b * G4;
                float gi_ = iv[r] + si  + bf2f(g0i[gbase + coli]);
                float gf_ = fv[r] + sf  + bf2f(g0i[gbase + coli + 512]);
                float gg_ = gv[r] + sgg + bf2f(g0i[gbase + coli + 1024]);
                float go_ = ov[r] + so  + bf2f(g0i[gbase + coli + 1536]);
                float cold = C[(size_t)b * HSZ + coli];
                float cn = sigf(gf_) * cold + sigf(gi_) * tanhfast(gg_);
                if (mode == 1) C[(size_t)b * HSZ + coli] = cn;
                if (T < 16) {
                    float h = qv[(size_t)b * DM + coli] + sigf(go_) * tanhfast(cn);
                    if (mode == 1) hqo[(size_t)b * DM + coli] = f2bf(h);
                    else           preg[r] += h * sg[coli];
                }
            }
        }
    }

    if (mode == 2) {
        #pragma unroll
        for (int r = 0; r < 4; ++r) {
            float p = preg[r];
            p += __shfl_xor(p, 1, 64);
            p += __shfl_xor(p, 2, 64);
            p += __shfl_xor(p, 4, 64);
            p += __shfl_xor(p, 8, 64);
            if (nl == 0) red[w][quad * 4 + r] = p;
        }
        __syncthreads();
        if (t < 16)
            atomicAdd(out + b0 + t, red[0][t] + red[1][t] + red[2][t] + red[3][t]);
    }
}

// ---------------------------------------------------------------------------
extern "C" void kernel_launch(void* const* d_in, const int* in_sizes, int n_in,
                              void* d_out, int out_size, void* d_ws, size_t ws_size,
                              hipStream_t stream) {
    const int* query   = (const int*)d_in[0];
    const int* support = (const int*)d_in[1];
    const int* q_l1 = (const int*)d_in[2];
    const int* q_l2 = (const int*)d_in[3];
    const int* q_r1 = (const int*)d_in[5];
    const int* q_r2 = (const int*)d_in[6];
    const int* s_l1 = (const int*)d_in[8];
    const int* s_l2 = (const int*)d_in[9];
    const int* s_r1 = (const int*)d_in[11];
    const int* s_r2 = (const int*)d_in[12];
    const float* emb    = (const float*)d_in[14];
    const float* gcn_W  = (const float*)d_in[15];
    const float* gcn_lb = (const float*)d_in[16];
    const float* gcn_b  = (const float*)d_in[17];
    const float* attn_W = (const float*)d_in[18];
    const float* attn_b = (const float*)d_in[19];
    const float* gate_W = (const float*)d_in[20];
    const float* gate_lb = (const float*)d_in[21];
    const float* gate_b  = (const float*)d_in[22];
    const float* p1_W = (const float*)d_in[23];
    const float* p1_b = (const float*)d_in[24];
    const float* p2_W = (const float*)d_in[25];
    const float* p2_b = (const float*)d_in[26];
    const float* ln_a = (const float*)d_in[27];
    const float* ln_b = (const float*)d_in[28];
    const float* Wih  = (const float*)d_in[29];
    const float* Whh  = (const float*)d_in[30];
    const float* bih  = (const float*)d_in[31];
    const float* bhh  = (const float*)d_in[32];

    // workspace layout: bf16 buffers first, then fp32
    unsigned short* P1   = (unsigned short*)d_ws;               // (V+1)*128
    unsigned short* P2   = P1 + (size_t)(VSZ + 1) * D;
    unsigned short* Wb   = P2 + (size_t)(VSZ + 1) * D;          // 256*128
    unsigned short* Wihp = Wb + 256 * 128;                      // 65536*8
    unsigned short* Whhp = Wihp + (size_t)65536 * 8;            // 65536*8
    unsigned short* g0b  = Whhp + (size_t)65536 * 8;            // NB*2048
    unsigned short* hqb  = g0b + (size_t)NB * G4;               // NB*256
    unsigned short* qvbf = hqb + (size_t)NB * DM;               // NB*256
    float* fws = (float*)(qvbf + (size_t)NB * DM);
    float* gbv = fws;  fws += G4;
    float* qvb = fws;  fws += (size_t)NB * DM;                  // 4 MB
    float* svb = fws;  fws += DM;
    float* sgb = fws;  fws += DM;
    float* sgW = fws;  fws += G4;
    float* Cb  = fws;  fws += (size_t)NB * HSZ;                 // 8 MB
    (void)in_sizes; (void)n_in; (void)out_size; (void)ws_size;

    k_wconv<<<128, 256, 0, stream>>>(gcn_W, Wb);
    k_pack<<<(131072 + 2048) / 256, 256, 0, stream>>>(
        Wih, Whh, bih, bhh, Wihp, Whhp, gbv);
    k_proj_mfma<<<(VSZ + 1 + 63) / 64, 256, 0, stream>>>(
        emb, Wb, gcn_lb, gcn_b, P1, P2, VSZ + 1);
    k_nbr<<<2 * (NB + 1), 256, 0, stream>>>(
        query, support, q_l1, q_l2, q_r1, q_r2, s_l1, s_l2, s_r1, s_r2,
        P1, P2, emb, attn_W, attn_b, gate_W, gate_lb, gate_b, qvb, qvbf, svb);
    k_sg<<<1, 256, 0, stream>>>(svb, p1_W, p1_b, p2_W, p2_b, ln_a, ln_b, sgb);
    k_sgwhh<<<G4 / 256, 256, 0, stream>>>(sgb, Whh, sgW);
    // step 1 (h_r = 0): A = qv bf16, B = Wih; store g0, C, hq
    k_lstm<<<dim3(NB / 16, 4), 256, 0, stream>>>(
        qvb, qvbf, Wihp, gbv, sgW, g0b, g0b, Cb, hqb, sgb, (float*)d_out, 0);
    // steps 2,3: A = hq, B = Whh[:, :256]; g = g0 + sgW + A@B
    k_lstm<<<dim3(NB / 16, 4), 256, 0, stream>>>(
        qvb, hqb, Whhp, gbv, sgW, g0b, g0b, Cb, hqb, sgb, (float*)d_out, 1);
    k_lstm<<<dim3(NB / 16, 4), 256, 0, stream>>>(
        qvb, hqb, Whhp, gbv, sgW, g0b, g0b, Cb, hqb, sgb, (float*)d_out, 1);
    // step 4: only cols < 256 matter -> y < 2; atomic dot into zeroed out
    k_zero<<<NB / 256, 256, 0, stream>>>((float*)d_out);
    k_lstm<<<dim3(NB / 16, 2), 256, 0, stream>>>(
        qvb, hqb, Whhp, gbv, sgW, g0b, g0b, Cb, hqb, sgb, (float*)d_out, 2);
}